// Round 8
// baseline (309.141 us; speedup 1.0000x reference)
//
#include <hip/hip_runtime.h>
#include <cstddef>

// B=2048, C_IN=C_OUT=64, T=32, E=32768, K_HOPS=2, KSIZE=3
#define NB   2048
#define NE   32768
#define NTC  2048      // T*C elems per node
#define SLOPE_F 0.01f
#define EPS_F   1e-5f

// bf16 helpers (manual, RNE pack)
__device__ __forceinline__ unsigned short f2bf(float f) {
    unsigned u = __builtin_bit_cast(unsigned, f);
    u += 0x7FFF + ((u >> 16) & 1);
    return (unsigned short)(u >> 16);
}
__device__ __forceinline__ float bff(unsigned short h) {
    return __builtin_bit_cast(float, (unsigned)h << 16);
}
__device__ __forceinline__ float bflo(unsigned v) {
    return __builtin_bit_cast(float, v << 16);
}
__device__ __forceinline__ float bfhi(unsigned v) {
    return __builtin_bit_cast(float, v & 0xFFFF0000u);
}
__device__ __forceinline__ unsigned pk2(float lo, float hi) {
    return (unsigned)f2bf(lo) | ((unsigned)f2bf(hi) << 16);
}
// unpack-accumulate 8 bf16 lanes of a uint4 into acc[0..7] (function, NOT a
// macro: R7's ACCV macro substituted its arg into the .w member token)
__device__ __forceinline__ void accv8(float* acc, const uint4& v, float wt) {
    acc[0] += wt * bflo(v.x); acc[1] += wt * bfhi(v.x);
    acc[2] += wt * bflo(v.y); acc[3] += wt * bfhi(v.y);
    acc[4] += wt * bflo(v.z); acc[5] += wt * bfhi(v.z);
    acc[6] += wt * bflo(v.w); acc[7] += wt * bfhi(v.w);
}

// ---------------- edge-index width handling ----------------
__global__ __launch_bounds__(256)
void k_detect(const int* __restrict__ ei, int* __restrict__ mode)
{
    int k = blockIdx.x * 256 + threadIdx.x;
    if (ei[2 * k + 1] != 0) atomicOr(mode, 1);  // 1 => int32 layout
}

__device__ __forceinline__ int edge_src(const int* ei, int m, int e) {
    return m ? ei[e] : ei[2 * e];
}
__device__ __forceinline__ int edge_dst(const int* ei, int m, int e) {
    return m ? ei[NE + e] : ei[2 * (NE + e)];
}

// hist + (first 16 blocks) conv-weight transpose+bf16 pack: wTb[i*64+o] = taps
__global__ __launch_bounds__(256)
void k_hist(const int* __restrict__ ei, const int* __restrict__ mode,
            int* __restrict__ hist, const float* __restrict__ cw,
            ushort4* __restrict__ wTb)
{
    int e = blockIdx.x * 256 + threadIdx.x;
    int m = *mode;
    atomicAdd(&hist[edge_dst(ei, m, e)], 1);
    if (blockIdx.x < 16) {
        int idx = e;                      // 0..4095
        int i = idx >> 6, o = idx & 63;
        ushort4 w;
        w.x = f2bf(cw[o * 192 + i * 3 + 0]);
        w.y = f2bf(cw[o * 192 + i * 3 + 1]);
        w.z = f2bf(cw[o * 192 + i * 3 + 2]);
        w.w = 0;
        wTb[idx] = w;
    }
}

// single block: CSR row-pointer scan
__global__ __launch_bounds__(256)
void k_scan(const int* __restrict__ hist, int* __restrict__ rowp, int* __restrict__ cur)
{
    __shared__ int part[256];
    int j = threadIdx.x;
    int loc[8]; int s = 0;
#pragma unroll
    for (int r = 0; r < 8; ++r) { loc[r] = hist[j * 8 + r]; s += loc[r]; }
    part[j] = s;
    __syncthreads();
    for (int off = 1; off < 256; off <<= 1) {
        int v = (j >= off) ? part[j - off] : 0;
        __syncthreads();
        part[j] += v;
        __syncthreads();
    }
    int excl = part[j] - s;
#pragma unroll
    for (int r = 0; r < 8; ++r) {
        rowp[j * 8 + r] = excl;
        cur [j * 8 + r] = excl;
        excl += loc[r];
    }
    if (j == 255) rowp[2048] = excl;  // == NE
}

__global__ __launch_bounds__(256)
void k_scat(const int* __restrict__ ei, const float* __restrict__ ew,
            const int* __restrict__ mode, int* __restrict__ cur,
            int* __restrict__ csrs, float* __restrict__ csrw)
{
    int e = blockIdx.x * 256 + threadIdx.x;
    int m = *mode;
    int d = edge_dst(ei, m, e);
    int pos = atomicAdd(&cur[d], 1);
    csrs[pos] = edge_src(ei, m, e);
    csrw[pos] = ew[e];
}

// ---------------- conv1d + leaky + LayerNorm + BN partials ----------------
// x read via per-lane VECTOR global loads at a wave-uniform address (base
// laundered through asm so uniformity analysis can't re-scalarize into
// s_load, which doubled FETCH in R6) -> TA coalesces 64 same-address lanes
// into one L1 access. Weights bf16 ushort4 (32KB, L1-resident). No LDS in
// the main loop.
__global__ __launch_bounds__(256, 8)
void k_convln(const float* __restrict__ x, const ushort4* __restrict__ wTb,
              const float* __restrict__ cb, const float* __restrict__ lg,
              const float* __restrict__ lb, float* __restrict__ h_in,
              float* __restrict__ partials)
{
    __shared__ float red1[64], red2[64];
    __shared__ float wsum[8];
    __shared__ float bcast[2];

    const int b = blockIdx.x, j = threadIdx.x;
    const float* __restrict__ xg = x + (size_t)b * NTC;
    const int o = j & 63, g = j >> 6;
    const int t0 = g * 8;                          // channel o, t in [t0,t0+8)

    if (j < 64) { red1[j] = 0.f; red2[j] = 0.f; }

    float acc[8];
    {
        float cbv = cb[o];
#pragma unroll
        for (int r = 0; r < 8; ++r) acc[r] = cbv;
    }
    const ushort4* wp = wTb + o;                   // per-lane, stride 64/i

    if (t0 == 0) {
        const float* xq = xg;
        asm volatile("" : "+v"(xq));               // force VMEM, not s_load
#pragma unroll 4
        for (int i = 0; i < 64; ++i) {
            ushort4 wq = wp[i * 64];               // 512B/wave, L1-hit
            float4 q0 = *(const float4*)(xq + i * 32);
            float4 q1 = *(const float4*)(xq + i * 32 + 4);
            float w0 = bff(wq.x), w1 = bff(wq.y), w2 = bff(wq.z);
            float X[10] = {0.f, 0.f, q0.x,q0.y,q0.z,q0.w, q1.x,q1.y,q1.z,q1.w};
#pragma unroll
            for (int r = 0; r < 8; ++r)
                acc[r] += X[r]*w0 + X[r+1]*w1 + X[r+2]*w2;
        }
    } else {
        const float* xq = xg + t0 - 4;             // 16B-aligned (t0 mult of 8)
        asm volatile("" : "+v"(xq));
#pragma unroll 4
        for (int i = 0; i < 64; ++i) {
            ushort4 wq = wp[i * 64];
            float4 qm = *(const float4*)(xq + i * 32);      // t0-4..t0-1
            float4 q0 = *(const float4*)(xq + i * 32 + 4);  // t0..t0+3
            float4 q1 = *(const float4*)(xq + i * 32 + 8);  // t0+4..t0+7
            float w0 = bff(wq.x), w1 = bff(wq.y), w2 = bff(wq.z);
            float X[10] = {qm.z, qm.w, q0.x,q0.y,q0.z,q0.w, q1.x,q1.y,q1.z,q1.w};
#pragma unroll
            for (int r = 0; r < 8; ++r)
                acc[r] += X[r]*w0 + X[r+1]*w1 + X[r+2]*w2;
        }
    }

    // leaky relu + local LN stats
    float s1 = 0.f, s2 = 0.f;
#pragma unroll
    for (int r = 0; r < 8; ++r) {
        float v = acc[r];
        v = (v >= 0.f) ? v : SLOPE_F * v;
        acc[r] = v;
        s1 += v; s2 += v * v;
    }
#pragma unroll
    for (int off = 32; off > 0; off >>= 1) {
        s1 += __shfl_down(s1, off, 64);
        s2 += __shfl_down(s2, off, 64);
    }
    if ((j & 63) == 0) { wsum[j >> 6] = s1; wsum[4 + (j >> 6)] = s2; }
    __syncthreads();
    if (j == 0) {
        float S1 = wsum[0] + wsum[1] + wsum[2] + wsum[3];
        float S2 = wsum[4] + wsum[5] + wsum[6] + wsum[7];
        float mu  = S1 * (1.f / 2048.f);
        float var = S2 * (1.f / 2048.f) - mu * mu;
        bcast[0] = mu;
        bcast[1] = rsqrtf(var + EPS_F);
    }
    __syncthreads();
    const float mu = bcast[0], rs = bcast[1];
    float hs1 = 0.f, hs2 = 0.f;
    float* hb = h_in + (size_t)b * NTC;
#pragma unroll
    for (int r = 0; r < 8; ++r) {
        int t = t0 + r;
        float h = (acc[r] - mu) * rs * lg[o * 32 + t] + lb[o * 32 + t];
        hb[t * 64 + o] = h;                        // coalesced: lanes span o
        hs1 += h; hs2 += h * h;
    }
    atomicAdd(&red1[o], hs1);                      // LDS atomics only
    atomicAdd(&red2[o], hs2);
    __syncthreads();
    float* pb_ = partials + (size_t)b * 128;       // coalesced 512B plain store
    if (j < 64)       pb_[j] = red1[j];
    else if (j < 128) pb_[j] = red2[j - 64];
}

// ---------------- reduce partials -> BN scale/shift ----------------
__global__ __launch_bounds__(256)
void k_bnred(const float* __restrict__ partials, const float* __restrict__ bg,
             const float* __restrict__ bb, float* __restrict__ stats)
{
    const int c = blockIdx.x, j = threadIdx.x;
    float s1 = 0.f, s2 = 0.f;
    for (int b = j; b < NB; b += 256) {
        const float* p = partials + (size_t)b * 128;
        s1 += p[c];
        s2 += p[64 + c];
    }
    __shared__ float r1[4], r2[4];
#pragma unroll
    for (int off = 32; off > 0; off >>= 1) {
        s1 += __shfl_down(s1, off, 64);
        s2 += __shfl_down(s2, off, 64);
    }
    if ((j & 63) == 0) { r1[j >> 6] = s1; r2[j >> 6] = s2; }
    __syncthreads();
    if (j == 0) {
        float S1 = r1[0] + r1[1] + r1[2] + r1[3];
        float S2 = r2[0] + r2[1] + r2[2] + r2[3];
        const float inv_n = 1.f / 65536.f;
        float mu  = S1 * inv_n;
        float var = S2 * inv_n - mu * mu;
        float rs  = rsqrtf(var + EPS_F);
        float sc  = bg[c] * rs;
        stats[128 + c] = sc;
        stats[192 + c] = bb[c] - mu * sc;
    }
}

// ---------------- z = leaky(BN(h)); out = h + z@W0 + tag_b; z -> bf16 ------
// W read from GLOBAL (16KB, L1-resident) per f-step: removes LDS b128
// broadcast pressure and the per-block W staging+sync.
__global__ __launch_bounds__(256, 8)
void k_zw0(const float* __restrict__ h_in, const float* __restrict__ stats,
           const float* __restrict__ tw, const float* __restrict__ tb,
           unsigned short* __restrict__ zb16, float* __restrict__ out)
{
    __shared__ float zl[32 * 65];
    __shared__ float hl[32 * 65];
    const int b = blockIdx.x, j = threadIdx.x;
    const int c = j & 63;
    const float sc = stats[128 + c], sh = stats[192 + c];
    const float* hb = h_in + (size_t)b * NTC;
    unsigned short* zb = zb16 + (size_t)b * NTC;
#pragma unroll
    for (int r = 0; r < 8; ++r) {
        int idx = j + r * 256;                    // idx = t*64 + c
        int t = idx >> 6;
        float h = hb[idx];
        float zv = h * sc + sh;
        zv = (zv >= 0.f) ? zv : SLOPE_F * zv;
        zb[idx] = f2bf(zv);                       // bf16 payload for hop1
        zl[t * 65 + c] = zv;
        hl[t * 65 + c] = h;
    }
    __syncthreads();
    const int t = j & 31, gq = (j >> 5) * 8;      // outputs (t, gq..gq+7)
    float accm[8];
#pragma unroll
    for (int r = 0; r < 8; ++r)
        accm[r] = tb[gq + r] + hl[t * 65 + gq + r];   // residual + bias
    const float4* Wg = (const float4*)(tw + gq);
    for (int f = 0; f < 64; ++f) {
        float zv = zl[t * 65 + f];
        float4 wa = Wg[f * 16];                   // tw + f*64 + gq, L1-hit
        float4 wb = Wg[f * 16 + 1];
        accm[0] += zv*wa.x; accm[1] += zv*wa.y; accm[2] += zv*wa.z; accm[3] += zv*wa.w;
        accm[4] += zv*wb.x; accm[5] += zv*wb.y; accm[6] += zv*wb.z; accm[7] += zv*wb.w;
    }
    float* ob = out + (size_t)b * NTC;            // out layout [b][c][t]
#pragma unroll
    for (int r = 0; r < 8; ++r)
        ob[(gq + r) * 32 + t] = accm[r];          // coalesced: lanes span t
}

// ---------------- one propagation hop (bf16 gather) + fused matmul ---------
__global__ __launch_bounds__(256, 8)
void k_hop(const unsigned short* __restrict__ p_in, const int* __restrict__ rowp,
           const int* __restrict__ csrs, const float* __restrict__ csrw,
           const float* __restrict__ tw, unsigned short* __restrict__ p_out,
           float* __restrict__ out)
{
    __shared__ float pl[32 * 65];
    const int d = blockIdx.x, j = threadIdx.x;
    const int beg = rowp[d], end = rowp[d + 1];
    float acc[8];
#pragma unroll
    for (int r = 0; r < 8; ++r) acc[r] = 0.f;
    int e = beg;
    for (; e + 4 <= end; e += 4) {                // 4 gathers in flight
        int s0 = csrs[e],  s1 = csrs[e+1], s2 = csrs[e+2], s3 = csrs[e+3];
        float w0 = csrw[e], w1 = csrw[e+1], w2 = csrw[e+2], w3 = csrw[e+3];
        uint4 v0 = ((const uint4*)(p_in + (size_t)s0 * NTC))[j];  // 16B = 8 bf16
        uint4 v1 = ((const uint4*)(p_in + (size_t)s1 * NTC))[j];
        uint4 v2 = ((const uint4*)(p_in + (size_t)s2 * NTC))[j];
        uint4 v3 = ((const uint4*)(p_in + (size_t)s3 * NTC))[j];
        accv8(acc, v0, w0); accv8(acc, v1, w1);
        accv8(acc, v2, w2); accv8(acc, v3, w3);
    }
    for (; e < end; ++e) {
        int s0 = csrs[e];
        float w0 = csrw[e];
        uint4 v0 = ((const uint4*)(p_in + (size_t)s0 * NTC))[j];
        accv8(acc, v0, w0);
    }
    if (p_out) {
        uint4 pv;
        pv.x = pk2(acc[0], acc[1]); pv.y = pk2(acc[2], acc[3]);
        pv.z = pk2(acc[4], acc[5]); pv.w = pk2(acc[6], acc[7]);
        ((uint4*)(p_out + (size_t)d * NTC))[j] = pv;
    }
    {
        int tt = j >> 3, c0 = (j & 7) * 8;        // thread owns elems j*8..+7
        float* q = &pl[tt * 65 + c0];
#pragma unroll
        for (int s = 0; s < 8; ++s) q[s] = acc[s];
    }
    __syncthreads();
    const int t = j & 31, gq = (j >> 5) * 8;
    float accm[8];
#pragma unroll
    for (int r = 0; r < 8; ++r) accm[r] = 0.f;
    const float4* Wg = (const float4*)(tw + gq);
    for (int f = 0; f < 64; ++f) {
        float pv = pl[t * 65 + f];
        float4 wa = Wg[f * 16];
        float4 wb = Wg[f * 16 + 1];
        accm[0] += pv*wa.x; accm[1] += pv*wa.y; accm[2] += pv*wa.z; accm[3] += pv*wa.w;
        accm[4] += pv*wb.x; accm[5] += pv*wb.y; accm[6] += pv*wb.z; accm[7] += pv*wb.w;
    }
    float* ob = out + (size_t)d * NTC;
#pragma unroll
    for (int r = 0; r < 8; ++r)
        ob[(gq + r) * 32 + t] += accm[r];         // block owns node d: safe RMW
}

// ---------------- launch ----------------
// workspace floats:
//   [0, 4194304)        h_in [b][t][c] fp32
//   [4194304, 6291456)  z_bf16  [b][t][c] (ushort, 8MB)
//   [6291456, 8388608)  p1_bf16 [b][t][c] (ushort, 8MB)
//   [8388608, +256)     stats (scale[64]@128, shift[64]@192)
//   [8388864, +16384)   wTb (bf16 ushort4 conv weights, 32KB used)
//   [8405248, +262144)  partials [b][128]
//   [8667392, ...)      ints: mode(4) hist(2048) rowp(2052) cur(2048)
//                             csrs(32768) csrw(32768)        (~35 MiB total)
extern "C" void kernel_launch(void* const* d_in, const int* in_sizes, int n_in,
                              void* d_out, int out_size, void* d_ws, size_t ws_size,
                              hipStream_t stream)
{
    const float* x  = (const float*)d_in[0];
    const int*   ei = (const int*)  d_in[1];
    const float* ew = (const float*)d_in[2];
    const float* cw = (const float*)d_in[3];
    const float* cb = (const float*)d_in[4];
    const float* lg = (const float*)d_in[5];
    const float* lb = (const float*)d_in[6];
    const float* bg = (const float*)d_in[7];
    const float* bb = (const float*)d_in[8];
    const float* tw = (const float*)d_in[9];
    const float* tb = (const float*)d_in[10];
    float* out = (float*)d_out;
    float* ws  = (float*)d_ws;

    float*          h_in  = ws;
    unsigned short* zbf   = (unsigned short*)(ws + 4194304);
    unsigned short* p1bf  = (unsigned short*)(ws + 6291456);
    float*          stats = ws + 8388608;
    ushort4*        wTb   = (ushort4*)(ws + 8388864);
    float*          parts = ws + 8405248;
    int*            ib    = (int*)(ws + 8667392);
    int*   mode  = ib;
    int*   hist  = ib + 4;
    int*   rowp  = ib + 2052;
    int*   cur   = ib + 4104;
    int*   csrs  = ib + 6152;
    float* csrw  = (float*)(ib + 38920);

    (void)hipMemsetAsync(ib, 0, 2052 * sizeof(int), stream);   // mode + hist

    k_detect <<<128, 256, 0, stream>>>(ei, mode);
    k_hist   <<<128, 256, 0, stream>>>(ei, mode, hist, cw, wTb);
    k_scan   <<<1,   256, 0, stream>>>(hist, rowp, cur);
    k_scat   <<<128, 256, 0, stream>>>(ei, ew, mode, cur, csrs, csrw);
    k_convln <<<NB,  256, 0, stream>>>(x, wTb, cb, lg, lb, h_in, parts);
    k_bnred  <<<64,  256, 0, stream>>>(parts, bg, bb, stats);
    k_zw0    <<<NB,  256, 0, stream>>>(h_in, stats, tw, tb, zbf, out);
    k_hop    <<<NB,  256, 0, stream>>>(zbf,  rowp, csrs, csrw, tw + 4096, p1bf, out);
    k_hop    <<<NB,  256, 0, stream>>>(p1bf, rowp, csrs, csrw, tw + 8192, nullptr, out);
}

// Round 9
// 218.603 us; speedup vs baseline: 1.4142x; 1.4142x over previous
//
#include <hip/hip_runtime.h>
#include <cstddef>

// B=2048, C_IN=C_OUT=64, T=32, E=32768, K_HOPS=2, KSIZE=3
#define NB   2048
#define NE   32768
#define NTC  2048      // T*C elems per node
#define SLOPE_F 0.01f
#define EPS_F   1e-5f

// bf16 helpers (manual, RNE pack)
__device__ __forceinline__ unsigned short f2bf(float f) {
    unsigned u = __builtin_bit_cast(unsigned, f);
    u += 0x7FFF + ((u >> 16) & 1);
    return (unsigned short)(u >> 16);
}
__device__ __forceinline__ float bflo(unsigned v) {
    return __builtin_bit_cast(float, v << 16);
}
__device__ __forceinline__ float bfhi(unsigned v) {
    return __builtin_bit_cast(float, v & 0xFFFF0000u);
}
__device__ __forceinline__ unsigned pk2(float lo, float hi) {
    return (unsigned)f2bf(lo) | ((unsigned)f2bf(hi) << 16);
}
// unpack-accumulate 8 bf16 lanes of a uint4 into acc[0..7]
__device__ __forceinline__ void accv8(float* acc, const uint4& v, float wt) {
    acc[0] += wt * bflo(v.x); acc[1] += wt * bfhi(v.x);
    acc[2] += wt * bflo(v.y); acc[3] += wt * bfhi(v.y);
    acc[4] += wt * bflo(v.z); acc[5] += wt * bfhi(v.z);
    acc[6] += wt * bflo(v.w); acc[7] += wt * bfhi(v.w);
}

// ---------------- edge-index width handling ----------------
__global__ __launch_bounds__(256)
void k_detect(const int* __restrict__ ei, int* __restrict__ mode)
{
    int k = blockIdx.x * 256 + threadIdx.x;
    if (ei[2 * k + 1] != 0) atomicOr(mode, 1);  // 1 => int32 layout
}

__device__ __forceinline__ int edge_src(const int* ei, int m, int e) {
    return m ? ei[e] : ei[2 * e];
}
__device__ __forceinline__ int edge_dst(const int* ei, int m, int e) {
    return m ? ei[NE + e] : ei[2 * (NE + e)];
}

// hist + (first 64 blocks) conv-weight transpose to fp32 wT4[i][o][4]
__global__ __launch_bounds__(256)
void k_hist(const int* __restrict__ ei, const int* __restrict__ mode,
            int* __restrict__ hist, const float* __restrict__ cw,
            float* __restrict__ wT4)
{
    int e = blockIdx.x * 256 + threadIdx.x;
    int m = *mode;
    atomicAdd(&hist[edge_dst(ei, m, e)], 1);
    if (blockIdx.x < 64) {
        int idx = e;                      // 0..16383
        int i = idx >> 8, o = (idx >> 2) & 63, k = idx & 3;
        wT4[idx] = (k < 3) ? cw[o * 192 + i * 3 + k] : 0.f;
    }
}

// single block: CSR row-pointer scan
__global__ __launch_bounds__(256)
void k_scan(const int* __restrict__ hist, int* __restrict__ rowp, int* __restrict__ cur)
{
    __shared__ int part[256];
    int j = threadIdx.x;
    int loc[8]; int s = 0;
#pragma unroll
    for (int r = 0; r < 8; ++r) { loc[r] = hist[j * 8 + r]; s += loc[r]; }
    part[j] = s;
    __syncthreads();
    for (int off = 1; off < 256; off <<= 1) {
        int v = (j >= off) ? part[j - off] : 0;
        __syncthreads();
        part[j] += v;
        __syncthreads();
    }
    int excl = part[j] - s;
#pragma unroll
    for (int r = 0; r < 8; ++r) {
        rowp[j * 8 + r] = excl;
        cur [j * 8 + r] = excl;
        excl += loc[r];
    }
    if (j == 255) rowp[2048] = excl;  // == NE
}

__global__ __launch_bounds__(256)
void k_scat(const int* __restrict__ ei, const float* __restrict__ ew,
            const int* __restrict__ mode, int* __restrict__ cur,
            int* __restrict__ csrs, float* __restrict__ csrw)
{
    int e = blockIdx.x * 256 + threadIdx.x;
    int m = *mode;
    int d = edge_dst(ei, m, e);
    int pos = atomicAdd(&cur[d], 1);
    csrs[pos] = edge_src(ei, m, e);
    csrw[pos] = ew[e];
}

// ---------------- conv1d + leaky + LayerNorm + BN partials ----------------
// R5 body verbatim (measured 44.8us): x staged in LDS, read wave-uniform
// (LDS broadcast = the cheapest measured broadcast path: ~26us pipe time vs
// readlane 30us VALU / VMEM-broadcast 55us / s_load K$-thrash). Weights fp32
// from global, per-lane distinct addresses (coalesced 1KB/wave). BN partials
// as one plain coalesced store (no contended atomics).
__global__ __launch_bounds__(256, 8)
void k_convln(const float* __restrict__ x, const float* __restrict__ wT4,
              const float* __restrict__ cb, const float* __restrict__ lg,
              const float* __restrict__ lb, float* __restrict__ h_in,
              float* __restrict__ partials)
{
    __shared__ __align__(16) float xp[64 * 36];   // xp[i][t+2]=x[i][t], zero pad
    __shared__ float red1[64], red2[64];
    __shared__ float wsum[8];
    __shared__ float bcast[2];

    const int b = blockIdx.x, j = threadIdx.x;
    const float* xb = x + (size_t)b * NTC;

#pragma unroll
    for (int r = 0; r < 8; ++r) {
        int idx = j + r * 256;                    // i = idx>>5, t = idx&31
        xp[(idx >> 5) * 36 + (idx & 31) + 2] = xb[idx];
    }
    {
        int i = j >> 2, s = j & 3;
        xp[i * 36 + ((s < 2) ? s : 32 + s)] = 0.f;  // zero pad slots 0,1,34,35
    }
    if (j < 64) { red1[j] = 0.f; red2[j] = 0.f; }
    __syncthreads();

    const int o = j & 63, g = j >> 6;
    const int t0 = g * 8;                         // channel o, t in [t0,t0+8)

    float acc[8];
    {
        float cbv = cb[o];
#pragma unroll
        for (int r = 0; r < 8; ++r) acc[r] = cbv;
    }
    const float4* wrow = (const float4*)wT4 + o;  // stride 64 float4s per i
    const float* xrow = &xp[t0];
    for (int ib = 0; ib < 16; ++ib) {
        float4 w0 = wrow[(ib * 4 + 0) * 64];
        float4 w1 = wrow[(ib * 4 + 1) * 64];
        float4 w2 = wrow[(ib * 4 + 2) * 64];
        float4 w3 = wrow[(ib * 4 + 3) * 64];
#pragma unroll
        for (int k = 0; k < 4; ++k) {
            const int i = ib * 4 + k;
            float4 wv = (k == 0) ? w0 : (k == 1) ? w1 : (k == 2) ? w2 : w3;
            const float* xr = xrow + i * 36;      // wave-uniform LDS broadcast
            float4 q0 = *(const float4*)(xr);
            float4 q1 = *(const float4*)(xr + 4);
            float2 q2 = *(const float2*)(xr + 8);
            float xw[10] = {q0.x,q0.y,q0.z,q0.w,q1.x,q1.y,q1.z,q1.w,q2.x,q2.y};
#pragma unroll
            for (int r = 0; r < 8; ++r)
                acc[r] += xw[r]*wv.x + xw[r+1]*wv.y + xw[r+2]*wv.z;
        }
    }
    // leaky relu + local LN stats
    float s1 = 0.f, s2 = 0.f;
#pragma unroll
    for (int r = 0; r < 8; ++r) {
        float v = acc[r];
        v = (v >= 0.f) ? v : SLOPE_F * v;
        acc[r] = v;
        s1 += v; s2 += v * v;
    }
#pragma unroll
    for (int off = 32; off > 0; off >>= 1) {
        s1 += __shfl_down(s1, off, 64);
        s2 += __shfl_down(s2, off, 64);
    }
    if ((j & 63) == 0) { wsum[j >> 6] = s1; wsum[4 + (j >> 6)] = s2; }
    __syncthreads();
    if (j == 0) {
        float S1 = wsum[0] + wsum[1] + wsum[2] + wsum[3];
        float S2 = wsum[4] + wsum[5] + wsum[6] + wsum[7];
        float mu  = S1 * (1.f / 2048.f);
        float var = S2 * (1.f / 2048.f) - mu * mu;
        bcast[0] = mu;
        bcast[1] = rsqrtf(var + EPS_F);
    }
    __syncthreads();
    const float mu = bcast[0], rs = bcast[1];
    float hs1 = 0.f, hs2 = 0.f;
    float* hb = h_in + (size_t)b * NTC;
#pragma unroll
    for (int r = 0; r < 8; ++r) {
        int t = t0 + r;
        float h = (acc[r] - mu) * rs * lg[o * 32 + t] + lb[o * 32 + t];
        hb[t * 64 + o] = h;                        // coalesced: lanes span o
        hs1 += h; hs2 += h * h;
    }
    atomicAdd(&red1[o], hs1);                      // LDS atomics only
    atomicAdd(&red2[o], hs2);
    __syncthreads();
    float* pb_ = partials + (size_t)b * 128;       // coalesced 512B plain store
    if (j < 64)       pb_[j] = red1[j];
    else if (j < 128) pb_[j] = red2[j - 64];
}

// ---------------- reduce partials -> BN scale/shift ----------------
__global__ __launch_bounds__(256)
void k_bnred(const float* __restrict__ partials, const float* __restrict__ bg,
             const float* __restrict__ bb, float* __restrict__ stats)
{
    const int c = blockIdx.x, j = threadIdx.x;
    float s1 = 0.f, s2 = 0.f;
    for (int b = j; b < NB; b += 256) {
        const float* p = partials + (size_t)b * 128;
        s1 += p[c];
        s2 += p[64 + c];
    }
    __shared__ float r1[4], r2[4];
#pragma unroll
    for (int off = 32; off > 0; off >>= 1) {
        s1 += __shfl_down(s1, off, 64);
        s2 += __shfl_down(s2, off, 64);
    }
    if ((j & 63) == 0) { r1[j >> 6] = s1; r2[j >> 6] = s2; }
    __syncthreads();
    if (j == 0) {
        float S1 = r1[0] + r1[1] + r1[2] + r1[3];
        float S2 = r2[0] + r2[1] + r2[2] + r2[3];
        const float inv_n = 1.f / 65536.f;
        float mu  = S1 * inv_n;
        float var = S2 * inv_n - mu * mu;
        float rs  = rsqrtf(var + EPS_F);
        float sc  = bg[c] * rs;
        stats[128 + c] = sc;
        stats[192 + c] = bb[c] - mu * sc;
    }
}

// ---------------- z = leaky(BN(h)); out = h + z@W0 + tag_b; z -> bf16 ------
// W staged in LDS (R5 pattern: b128 reads, 2 distinct addrs/wave -> free
// broadcast). R8's W-from-global VMEM broadcast regressed; reverted.
__global__ __launch_bounds__(256, 4)
void k_zw0(const float* __restrict__ h_in, const float* __restrict__ stats,
           const float* __restrict__ tw, const float* __restrict__ tb,
           unsigned short* __restrict__ zb16, float* __restrict__ out)
{
    __shared__ float zl[32 * 65];
    __shared__ float hl[32 * 65];
    __shared__ __align__(16) float W[64 * 64];
    const int b = blockIdx.x, j = threadIdx.x;
#pragma unroll
    for (int r = 0; r < 16; ++r) { int idx = j + r * 256; W[idx] = tw[idx]; }
    const int c = j & 63;
    const float sc = stats[128 + c], sh = stats[192 + c];
    const float* hb = h_in + (size_t)b * NTC;
    unsigned short* zb = zb16 + (size_t)b * NTC;
#pragma unroll
    for (int r = 0; r < 8; ++r) {
        int idx = j + r * 256;                    // idx = t*64 + c
        int t = idx >> 6;
        float h = hb[idx];
        float zv = h * sc + sh;
        zv = (zv >= 0.f) ? zv : SLOPE_F * zv;
        zb[idx] = f2bf(zv);                       // bf16 payload for hop1
        zl[t * 65 + c] = zv;
        hl[t * 65 + c] = h;
    }
    __syncthreads();
    const int t = j & 31, gq = (j >> 5) * 8;      // outputs (t, gq..gq+7)
    float accm[8];
#pragma unroll
    for (int r = 0; r < 8; ++r)
        accm[r] = tb[gq + r] + hl[t * 65 + gq + r];   // residual + bias
    for (int f = 0; f < 64; ++f) {
        float zv = zl[t * 65 + f];
        const float4* Wr = (const float4*)&W[f * 64 + gq];
        float4 wa = Wr[0], wb = Wr[1];
        accm[0] += zv*wa.x; accm[1] += zv*wa.y; accm[2] += zv*wa.z; accm[3] += zv*wa.w;
        accm[4] += zv*wb.x; accm[5] += zv*wb.y; accm[6] += zv*wb.z; accm[7] += zv*wb.w;
    }
    float* ob = out + (size_t)b * NTC;            // out layout [b][c][t]
#pragma unroll
    for (int r = 0; r < 8; ++r)
        ob[(gq + r) * 32 + t] = accm[r];          // coalesced: lanes span t
}

// ---------------- one propagation hop (bf16 gather) + fused matmul ---------
__global__ __launch_bounds__(256, 6)
void k_hop(const unsigned short* __restrict__ p_in, const int* __restrict__ rowp,
           const int* __restrict__ csrs, const float* __restrict__ csrw,
           const float* __restrict__ tw, unsigned short* __restrict__ p_out,
           float* __restrict__ out)
{
    __shared__ float pl[32 * 65];
    __shared__ __align__(16) float W[64 * 64];
    const int d = blockIdx.x, j = threadIdx.x;
#pragma unroll
    for (int r = 0; r < 16; ++r) { int idx = j + r * 256; W[idx] = tw[idx]; }
    const int beg = rowp[d], end = rowp[d + 1];
    float acc[8];
#pragma unroll
    for (int r = 0; r < 8; ++r) acc[r] = 0.f;
    int e = beg;
    for (; e + 4 <= end; e += 4) {                // 4 gathers in flight
        int s0 = csrs[e],  s1 = csrs[e+1], s2 = csrs[e+2], s3 = csrs[e+3];
        float w0 = csrw[e], w1 = csrw[e+1], w2 = csrw[e+2], w3 = csrw[e+3];
        uint4 v0 = ((const uint4*)(p_in + (size_t)s0 * NTC))[j];  // 16B = 8 bf16
        uint4 v1 = ((const uint4*)(p_in + (size_t)s1 * NTC))[j];
        uint4 v2 = ((const uint4*)(p_in + (size_t)s2 * NTC))[j];
        uint4 v3 = ((const uint4*)(p_in + (size_t)s3 * NTC))[j];
        accv8(acc, v0, w0); accv8(acc, v1, w1);
        accv8(acc, v2, w2); accv8(acc, v3, w3);
    }
    for (; e < end; ++e) {
        int s0 = csrs[e];
        float w0 = csrw[e];
        uint4 v0 = ((const uint4*)(p_in + (size_t)s0 * NTC))[j];
        accv8(acc, v0, w0);
    }
    if (p_out) {
        uint4 pv;
        pv.x = pk2(acc[0], acc[1]); pv.y = pk2(acc[2], acc[3]);
        pv.z = pk2(acc[4], acc[5]); pv.w = pk2(acc[6], acc[7]);
        ((uint4*)(p_out + (size_t)d * NTC))[j] = pv;
    }
    {
        int tt = j >> 3, c0 = (j & 7) * 8;        // thread owns elems j*8..+7
        float* q = &pl[tt * 65 + c0];
#pragma unroll
        for (int s = 0; s < 8; ++s) q[s] = acc[s];
    }
    __syncthreads();
    const int t = j & 31, gq = (j >> 5) * 8;
    float accm[8];
#pragma unroll
    for (int r = 0; r < 8; ++r) accm[r] = 0.f;
    for (int f = 0; f < 64; ++f) {
        float pv = pl[t * 65 + f];
        const float4* Wr = (const float4*)&W[f * 64 + gq];
        float4 wa = Wr[0], wb = Wr[1];
        accm[0] += pv*wa.x; accm[1] += pv*wa.y; accm[2] += pv*wa.z; accm[3] += pv*wa.w;
        accm[4] += pv*wb.x; accm[5] += pv*wb.y; accm[6] += pv*wb.z; accm[7] += pv*wb.w;
    }
    float* ob = out + (size_t)d * NTC;
#pragma unroll
    for (int r = 0; r < 8; ++r)
        ob[(gq + r) * 32 + t] += accm[r];         // block owns node d: safe RMW
}

// ---------------- launch ----------------
// workspace floats:
//   [0, 4194304)        h_in [b][t][c] fp32
//   [4194304, 6291456)  z_bf16  [b][t][c] (ushort, 8MB)
//   [6291456, 8388608)  p1_bf16 [b][t][c] (ushort, 8MB)
//   [8388608, +256)     stats (scale[64]@128, shift[64]@192)
//   [8388864, +16384)   wT4 (fp32 transposed conv weights)
//   [8405248, +262144)  partials [b][128]
//   [8667392, ...)      ints: mode(4) hist(2048) rowp(2052) cur(2048)
//                             csrs(32768) csrw(32768)        (~35 MiB total)
extern "C" void kernel_launch(void* const* d_in, const int* in_sizes, int n_in,
                              void* d_out, int out_size, void* d_ws, size_t ws_size,
                              hipStream_t stream)
{
    const float* x  = (const float*)d_in[0];
    const int*   ei = (const int*)  d_in[1];
    const float* ew = (const float*)d_in[2];
    const float* cw = (const float*)d_in[3];
    const float* cb = (const float*)d_in[4];
    const float* lg = (const float*)d_in[5];
    const float* lb = (const float*)d_in[6];
    const float* bg = (const float*)d_in[7];
    const float* bb = (const float*)d_in[8];
    const float* tw = (const float*)d_in[9];
    const float* tb = (const float*)d_in[10];
    float* out = (float*)d_out;
    float* ws  = (float*)d_ws;

    float*          h_in  = ws;
    unsigned short* zbf   = (unsigned short*)(ws + 4194304);
    unsigned short* p1bf  = (unsigned short*)(ws + 6291456);
    float*          stats = ws + 8388608;
    float*          wT4   = ws + 8388864;
    float*          parts = ws + 8405248;
    int*            ib    = (int*)(ws + 8667392);
    int*   mode  = ib;
    int*   hist  = ib + 4;
    int*   rowp  = ib + 2052;
    int*   cur   = ib + 4104;
    int*   csrs  = ib + 6152;
    float* csrw  = (float*)(ib + 38920);

    (void)hipMemsetAsync(ib, 0, 2052 * sizeof(int), stream);   // mode + hist

    k_detect <<<128, 256, 0, stream>>>(ei, mode);
    k_hist   <<<128, 256, 0, stream>>>(ei, mode, hist, cw, wT4);
    k_scan   <<<1,   256, 0, stream>>>(hist, rowp, cur);
    k_scat   <<<128, 256, 0, stream>>>(ei, ew, mode, cur, csrs, csrw);
    k_convln <<<NB,  256, 0, stream>>>(x, wT4, cb, lg, lb, h_in, parts);
    k_bnred  <<<64,  256, 0, stream>>>(parts, bg, bb, stats);
    k_zw0    <<<NB,  256, 0, stream>>>(h_in, stats, tw, tb, zbf, out);
    k_hop    <<<NB,  256, 0, stream>>>(zbf,  rowp, csrs, csrw, tw + 4096, p1bf, out);
    k_hop    <<<NB,  256, 0, stream>>>(p1bf, rowp, csrs, csrw, tw + 8192, nullptr, out);
}

// Round 10
// 216.289 us; speedup vs baseline: 1.4293x; 1.0107x over previous
//
#include <hip/hip_runtime.h>
#include <cstddef>

// B=2048, C_IN=C_OUT=64, T=32, E=32768, K_HOPS=2, KSIZE=3
#define NB   2048
#define NE   32768
#define NTC  2048      // T*C elems per node
#define SLOPE_F 0.01f
#define EPS_F   1e-5f

typedef short bf16x8 __attribute__((ext_vector_type(8)));
typedef float f32x4  __attribute__((ext_vector_type(4)));

// bf16 helpers (manual, RNE pack)
__device__ __forceinline__ unsigned short f2bf(float f) {
    unsigned u = __builtin_bit_cast(unsigned, f);
    u += 0x7FFF + ((u >> 16) & 1);
    return (unsigned short)(u >> 16);
}
__device__ __forceinline__ float bflo(unsigned v) {
    return __builtin_bit_cast(float, v << 16);
}
__device__ __forceinline__ float bfhi(unsigned v) {
    return __builtin_bit_cast(float, v & 0xFFFF0000u);
}
__device__ __forceinline__ unsigned pk2(float lo, float hi) {
    return (unsigned)f2bf(lo) | ((unsigned)f2bf(hi) << 16);
}
// unpack-accumulate 8 bf16 lanes of a uint4 into acc[0..7]
__device__ __forceinline__ void accv8(float* acc, const uint4& v, float wt) {
    acc[0] += wt * bflo(v.x); acc[1] += wt * bfhi(v.x);
    acc[2] += wt * bflo(v.y); acc[3] += wt * bfhi(v.y);
    acc[4] += wt * bflo(v.z); acc[5] += wt * bfhi(v.z);
    acc[6] += wt * bflo(v.w); acc[7] += wt * bfhi(v.w);
}

// ---------------- edge-index width handling ----------------
__global__ __launch_bounds__(256)
void k_detect(const int* __restrict__ ei, int* __restrict__ mode)
{
    int k = blockIdx.x * 256 + threadIdx.x;
    if (ei[2 * k + 1] != 0) atomicOr(mode, 1);  // 1 => int32 layout
}

__device__ __forceinline__ int edge_src(const int* ei, int m, int e) {
    return m ? ei[e] : ei[2 * e];
}
__device__ __forceinline__ int edge_dst(const int* ei, int m, int e) {
    return m ? ei[NE + e] : ei[2 * (NE + e)];
}

// hist + (first 48 blocks) conv-weight pack: wAb[(kk*64+o)*64+i] = bf16 w[o][i][kk]
// (A-operand-friendly layout: o-major, i contiguous)
__global__ __launch_bounds__(256)
void k_hist(const int* __restrict__ ei, const int* __restrict__ mode,
            int* __restrict__ hist, const float* __restrict__ cw,
            unsigned short* __restrict__ wAb)
{
    int e = blockIdx.x * 256 + threadIdx.x;
    int m = *mode;
    atomicAdd(&hist[edge_dst(ei, m, e)], 1);
    if (blockIdx.x < 48) {
        int idx = e;                      // 0..12287
        int kk = idx >> 12, o = (idx >> 6) & 63, i = idx & 63;
        wAb[idx] = f2bf(cw[o * 192 + i * 3 + kk]);
    }
}

// single block: CSR row-pointer scan
__global__ __launch_bounds__(256)
void k_scan(const int* __restrict__ hist, int* __restrict__ rowp, int* __restrict__ cur)
{
    __shared__ int part[256];
    int j = threadIdx.x;
    int loc[8]; int s = 0;
#pragma unroll
    for (int r = 0; r < 8; ++r) { loc[r] = hist[j * 8 + r]; s += loc[r]; }
    part[j] = s;
    __syncthreads();
    for (int off = 1; off < 256; off <<= 1) {
        int v = (j >= off) ? part[j - off] : 0;
        __syncthreads();
        part[j] += v;
        __syncthreads();
    }
    int excl = part[j] - s;
#pragma unroll
    for (int r = 0; r < 8; ++r) {
        rowp[j * 8 + r] = excl;
        cur [j * 8 + r] = excl;
        excl += loc[r];
    }
    if (j == 255) rowp[2048] = excl;  // == NE
}

__global__ __launch_bounds__(256)
void k_scat(const int* __restrict__ ei, const float* __restrict__ ew,
            const int* __restrict__ mode, int* __restrict__ cur,
            int* __restrict__ csrs, float* __restrict__ csrw)
{
    int e = blockIdx.x * 256 + threadIdx.x;
    int m = *mode;
    int d = edge_dst(ei, m, e);
    int pos = atomicAdd(&cur[d], 1);
    csrs[pos] = edge_src(ei, m, e);
    csrw[pos] = ew[e];
}

// ---------------- conv1d (MFMA) + leaky + LayerNorm + BN partials ----------
// Per block: 3 tap-GEMMs M64(o) x K64(i) x N32(t) on 16x16x32 bf16 MFMA.
// x staged once as bf16 xT[tp][i] (tp = t+2, row stride 72 -> <=2-way bank
// aliasing, free); B-frag = contiguous 16B of xT row. Weights = per-lane
// coalesced 16B global loads (L1-resident, no broadcast of any kind).
// Lane mapping (verified layouts): A m=lane&15,k=quad*8+j; B n=lane&15,
// k=quad*8+j; D n=lane&15, m=quad*4+reg.
__global__ __launch_bounds__(256, 8)
void k_convln(const float* __restrict__ x, const unsigned short* __restrict__ wAb,
              const float* __restrict__ cb, const float* __restrict__ lg,
              const float* __restrict__ lb, float* __restrict__ h_in,
              float* __restrict__ partials)
{
    __shared__ __align__(16) unsigned short xT[36 * 72];
    __shared__ float red1[64], red2[64];
    __shared__ float wsum[8];
    __shared__ float bcast[2];

    const int b = blockIdx.x, j = threadIdx.x;
    const float* __restrict__ xg = x + (size_t)b * NTC;

    {   // stage x -> bf16 xT[t+2][i]; zero-pad rows 0,1,34,35
        unsigned* xTd = (unsigned*)xT;
        int t = j & 31, p = j >> 5;
#pragma unroll
        for (int r = 0; r < 4; ++r) {
            int i0 = (r * 8 + p) * 2;
            float v0 = xg[i0 * 32 + t];
            float v1 = xg[(i0 + 1) * 32 + t];
            xTd[(t + 2) * 36 + (i0 >> 1)] = pk2(v0, v1);
        }
        if (j < 72)       xTd[j] = 0u;
        else if (j < 144) xTd[1224 + (j - 72)] = 0u;   // rows 34,35
    }
    if (j < 64) { red1[j] = 0.f; red2[j] = 0.f; }
    __syncthreads();

    const int lane = j & 63, w = j >> 6;      // wave w owns o-tile w*16..w*16+15
    const int n16 = lane & 15, quad = lane >> 4;

    bf16x8 afr[3][2];                          // A frags: [tap][Kstep]
#pragma unroll
    for (int kk = 0; kk < 3; ++kk)
#pragma unroll
        for (int s = 0; s < 2; ++s) {
            int off16 = (kk * 64 + w * 16 + n16) * 64 + s * 32 + quad * 8;
            afr[kk][s] = *(const bf16x8*)(wAb + off16);
        }

    f32x4 acc0 = {0.f, 0.f, 0.f, 0.f};        // N-tile 0 (t = n16)
    f32x4 acc1 = {0.f, 0.f, 0.f, 0.f};        // N-tile 1 (t = 16+n16)
#pragma unroll
    for (int kk = 0; kk < 3; ++kk)
#pragma unroll
        for (int s = 0; s < 2; ++s) {
            bf16x8 b0 = *(const bf16x8*)(xT + (n16 + kk) * 72 + s * 32 + quad * 8);
            bf16x8 b1 = *(const bf16x8*)(xT + (16 + n16 + kk) * 72 + s * 32 + quad * 8);
            acc0 = __builtin_amdgcn_mfma_f32_16x16x32_bf16(afr[kk][s], b0, acc0, 0, 0, 0);
            acc1 = __builtin_amdgcn_mfma_f32_16x16x32_bf16(afr[kk][s], b1, acc1, 0, 0, 0);
        }

    // epilogue: +bias, leaky, LN stats
    float vals[2][4];
    float s1 = 0.f, s2 = 0.f;
#pragma unroll
    for (int r = 0; r < 4; ++r) {
        float cbv = cb[w * 16 + quad * 4 + r];
        float v0 = acc0[r] + cbv;
        float v1 = acc1[r] + cbv;
        v0 = (v0 >= 0.f) ? v0 : SLOPE_F * v0;
        v1 = (v1 >= 0.f) ? v1 : SLOPE_F * v1;
        vals[0][r] = v0; vals[1][r] = v1;
        s1 += v0 + v1; s2 += v0 * v0 + v1 * v1;
    }
#pragma unroll
    for (int off = 32; off > 0; off >>= 1) {
        s1 += __shfl_down(s1, off, 64);
        s2 += __shfl_down(s2, off, 64);
    }
    if (lane == 0) { wsum[w] = s1; wsum[4 + w] = s2; }
    __syncthreads();
    if (j == 0) {
        float S1 = wsum[0] + wsum[1] + wsum[2] + wsum[3];
        float S2 = wsum[4] + wsum[5] + wsum[6] + wsum[7];
        float mu  = S1 * (1.f / 2048.f);
        float var = S2 * (1.f / 2048.f) - mu * mu;
        bcast[0] = mu;
        bcast[1] = rsqrtf(var + EPS_F);
    }
    __syncthreads();
    const float mu = bcast[0], rs = bcast[1];
    float* hb = h_in + (size_t)b * NTC;
    float po1[4] = {0.f, 0.f, 0.f, 0.f}, po2[4] = {0.f, 0.f, 0.f, 0.f};
#pragma unroll
    for (int nt = 0; nt < 2; ++nt) {
        int t = nt * 16 + n16;
#pragma unroll
        for (int r = 0; r < 4; ++r) {
            int o = w * 16 + quad * 4 + r;
            float h = (vals[nt][r] - mu) * rs * lg[o * 32 + t] + lb[o * 32 + t];
            hb[t * 64 + o] = h;
            po1[r] += h; po2[r] += h * h;
        }
    }
#pragma unroll
    for (int r = 0; r < 4; ++r) {
        int o = w * 16 + quad * 4 + r;
        atomicAdd(&red1[o], po1[r]);           // LDS atomics only
        atomicAdd(&red2[o], po2[r]);
    }
    __syncthreads();
    float* pb_ = partials + (size_t)b * 128;   // coalesced 512B plain store
    if (j < 64)       pb_[j] = red1[j];
    else if (j < 128) pb_[j] = red2[j - 64];
}

// ---------------- reduce partials -> BN scale/shift ----------------
__global__ __launch_bounds__(256)
void k_bnred(const float* __restrict__ partials, const float* __restrict__ bg,
             const float* __restrict__ bb, float* __restrict__ stats)
{
    const int c = blockIdx.x, j = threadIdx.x;
    float s1 = 0.f, s2 = 0.f;
    for (int b = j; b < NB; b += 256) {
        const float* p = partials + (size_t)b * 128;
        s1 += p[c];
        s2 += p[64 + c];
    }
    __shared__ float r1[4], r2[4];
#pragma unroll
    for (int off = 32; off > 0; off >>= 1) {
        s1 += __shfl_down(s1, off, 64);
        s2 += __shfl_down(s2, off, 64);
    }
    if ((j & 63) == 0) { r1[j >> 6] = s1; r2[j >> 6] = s2; }
    __syncthreads();
    if (j == 0) {
        float S1 = r1[0] + r1[1] + r1[2] + r1[3];
        float S2 = r2[0] + r2[1] + r2[2] + r2[3];
        const float inv_n = 1.f / 65536.f;
        float mu  = S1 * inv_n;
        float var = S2 * inv_n - mu * mu;
        float rs  = rsqrtf(var + EPS_F);
        float sc  = bg[c] * rs;
        stats[128 + c] = sc;
        stats[192 + c] = bb[c] - mu * sc;
    }
}

// ---------------- z = leaky(BN(h)); out = h + z@W0 + tag_b; z -> bf16 ------
// W staged in LDS (b128 reads, 2 distinct addrs/wave -> free broadcast).
__global__ __launch_bounds__(256, 4)
void k_zw0(const float* __restrict__ h_in, const float* __restrict__ stats,
           const float* __restrict__ tw, const float* __restrict__ tb,
           unsigned short* __restrict__ zb16, float* __restrict__ out)
{
    __shared__ float zl[32 * 65];
    __shared__ float hl[32 * 65];
    __shared__ __align__(16) float W[64 * 64];
    const int b = blockIdx.x, j = threadIdx.x;
#pragma unroll
    for (int r = 0; r < 16; ++r) { int idx = j + r * 256; W[idx] = tw[idx]; }
    const int c = j & 63;
    const float sc = stats[128 + c], sh = stats[192 + c];
    const float* hb = h_in + (size_t)b * NTC;
    unsigned short* zb = zb16 + (size_t)b * NTC;
#pragma unroll
    for (int r = 0; r < 8; ++r) {
        int idx = j + r * 256;                    // idx = t*64 + c
        int t = idx >> 6;
        float h = hb[idx];
        float zv = h * sc + sh;
        zv = (zv >= 0.f) ? zv : SLOPE_F * zv;
        zb[idx] = f2bf(zv);                       // bf16 payload for hop1
        zl[t * 65 + c] = zv;
        hl[t * 65 + c] = h;
    }
    __syncthreads();
    const int t = j & 31, gq = (j >> 5) * 8;      // outputs (t, gq..gq+7)
    float accm[8];
#pragma unroll
    for (int r = 0; r < 8; ++r)
        accm[r] = tb[gq + r] + hl[t * 65 + gq + r];   // residual + bias
    for (int f = 0; f < 64; ++f) {
        float zv = zl[t * 65 + f];
        const float4* Wr = (const float4*)&W[f * 64 + gq];
        float4 wa = Wr[0], wb = Wr[1];
        accm[0] += zv*wa.x; accm[1] += zv*wa.y; accm[2] += zv*wa.z; accm[3] += zv*wa.w;
        accm[4] += zv*wb.x; accm[5] += zv*wb.y; accm[6] += zv*wb.z; accm[7] += zv*wb.w;
    }
    float* ob = out + (size_t)b * NTC;            // out layout [b][c][t]
#pragma unroll
    for (int r = 0; r < 8; ++r)
        ob[(gq + r) * 32 + t] = accm[r];          // coalesced: lanes span t
}

// ---------------- one propagation hop (bf16 gather) + fused matmul ---------
__global__ __launch_bounds__(256, 6)
void k_hop(const unsigned short* __restrict__ p_in, const int* __restrict__ rowp,
           const int* __restrict__ csrs, const float* __restrict__ csrw,
           const float* __restrict__ tw, unsigned short* __restrict__ p_out,
           float* __restrict__ out)
{
    __shared__ float pl[32 * 65];
    __shared__ __align__(16) float W[64 * 64];
    const int d = blockIdx.x, j = threadIdx.x;
#pragma unroll
    for (int r = 0; r < 16; ++r) { int idx = j + r * 256; W[idx] = tw[idx]; }
    const int beg = rowp[d], end = rowp[d + 1];
    float acc[8];
#pragma unroll
    for (int r = 0; r < 8; ++r) acc[r] = 0.f;
    int e = beg;
    for (; e + 4 <= end; e += 4) {                // 4 gathers in flight
        int s0 = csrs[e],  s1 = csrs[e+1], s2 = csrs[e+2], s3 = csrs[e+3];
        float w0 = csrw[e], w1 = csrw[e+1], w2 = csrw[e+2], w3 = csrw[e+3];
        uint4 v0 = ((const uint4*)(p_in + (size_t)s0 * NTC))[j];  // 16B = 8 bf16
        uint4 v1 = ((const uint4*)(p_in + (size_t)s1 * NTC))[j];
        uint4 v2 = ((const uint4*)(p_in + (size_t)s2 * NTC))[j];
        uint4 v3 = ((const uint4*)(p_in + (size_t)s3 * NTC))[j];
        accv8(acc, v0, w0); accv8(acc, v1, w1);
        accv8(acc, v2, w2); accv8(acc, v3, w3);
    }
    for (; e < end; ++e) {
        int s0 = csrs[e];
        float w0 = csrw[e];
        uint4 v0 = ((const uint4*)(p_in + (size_t)s0 * NTC))[j];
        accv8(acc, v0, w0);
    }
    if (p_out) {
        uint4 pv;
        pv.x = pk2(acc[0], acc[1]); pv.y = pk2(acc[2], acc[3]);
        pv.z = pk2(acc[4], acc[5]); pv.w = pk2(acc[6], acc[7]);
        ((uint4*)(p_out + (size_t)d * NTC))[j] = pv;
    }
    {
        int tt = j >> 3, c0 = (j & 7) * 8;        // thread owns elems j*8..+7
        float* q = &pl[tt * 65 + c0];
#pragma unroll
        for (int s = 0; s < 8; ++s) q[s] = acc[s];
    }
    __syncthreads();
    const int t = j & 31, gq = (j >> 5) * 8;
    float accm[8];
#pragma unroll
    for (int r = 0; r < 8; ++r) accm[r] = 0.f;
    for (int f = 0; f < 64; ++f) {
        float pv = pl[t * 65 + f];
        const float4* Wr = (const float4*)&W[f * 64 + gq];
        float4 wa = Wr[0], wb = Wr[1];
        accm[0] += pv*wa.x; accm[1] += pv*wa.y; accm[2] += pv*wa.z; accm[3] += pv*wa.w;
        accm[4] += pv*wb.x; accm[5] += pv*wb.y; accm[6] += pv*wb.z; accm[7] += pv*wb.w;
    }
    float* ob = out + (size_t)d * NTC;
#pragma unroll
    for (int r = 0; r < 8; ++r)
        ob[(gq + r) * 32 + t] += accm[r];         // block owns node d: safe RMW
}

// ---------------- launch ----------------
// workspace floats:
//   [0, 4194304)        h_in [b][t][c] fp32
//   [4194304, 6291456)  z_bf16  [b][t][c] (ushort, 8MB)
//   [6291456, 8388608)  p1_bf16 [b][t][c] (ushort, 8MB)
//   [8388608, +256)     stats (scale[64]@128, shift[64]@192)
//   [8388864, +16384)   wAb (bf16 A-layout conv weights, 24KB used)
//   [8405248, +262144)  partials [b][128]
//   [8667392, ...)      ints: mode(4) hist(2048) rowp(2052) cur(2048)
//                             csrs(32768) csrw(32768)        (~35 MiB total)
extern "C" void kernel_launch(void* const* d_in, const int* in_sizes, int n_in,
                              void* d_out, int out_size, void* d_ws, size_t ws_size,
                              hipStream_t stream)
{
    const float* x  = (const float*)d_in[0];
    const int*   ei = (const int*)  d_in[1];
    const float* ew = (const float*)d_in[2];
    const float* cw = (const float*)d_in[3];
    const float* cb = (const float*)d_in[4];
    const float* lg = (const float*)d_in[5];
    const float* lb = (const float*)d_in[6];
    const float* bg = (const float*)d_in[7];
    const float* bb = (const float*)d_in[8];
    const float* tw = (const float*)d_in[9];
    const float* tb = (const float*)d_in[10];
    float* out = (float*)d_out;
    float* ws  = (float*)d_ws;

    float*          h_in  = ws;
    unsigned short* zbf   = (unsigned short*)(ws + 4194304);
    unsigned short* p1bf  = (unsigned short*)(ws + 6291456);
    float*          stats = ws + 8388608;
    unsigned short* wAb   = (unsigned short*)(ws + 8388864);
    float*          parts = ws + 8405248;
    int*            ib    = (int*)(ws + 8667392);
    int*   mode  = ib;
    int*   hist  = ib + 4;
    int*   rowp  = ib + 2052;
    int*   cur   = ib + 4104;
    int*   csrs  = ib + 6152;
    float* csrw  = (float*)(ib + 38920);

    (void)hipMemsetAsync(ib, 0, 2052 * sizeof(int), stream);   // mode + hist

    k_detect <<<128, 256, 0, stream>>>(ei, mode);
    k_hist   <<<128, 256, 0, stream>>>(ei, mode, hist, cw, wAb);
    k_scan   <<<1,   256, 0, stream>>>(hist, rowp, cur);
    k_scat   <<<128, 256, 0, stream>>>(ei, ew, mode, cur, csrs, csrw);
    k_convln <<<NB,  256, 0, stream>>>(x, wAb, cb, lg, lb, h_in, parts);
    k_bnred  <<<64,  256, 0, stream>>>(parts, bg, bb, stats);
    k_zw0    <<<NB,  256, 0, stream>>>(h_in, stats, tw, tb, zbf, out);
    k_hop    <<<NB,  256, 0, stream>>>(zbf,  rowp, csrs, csrw, tw + 4096, p1bf, out);
    k_hop    <<<NB,  256, 0, stream>>>(p1bf, rowp, csrs, csrw, tw + 8192, nullptr, out);
}

// Round 11
// 198.631 us; speedup vs baseline: 1.5564x; 1.0889x over previous
//
#include <hip/hip_runtime.h>
#include <cstddef>

// B=2048, C_IN=C_OUT=64, T=32, E=32768, K_HOPS=2, KSIZE=3
#define NB   2048
#define NE   32768
#define NTC  2048      // T*C elems per node
#define SLOPE_F 0.01f
#define EPS_F   1e-5f

typedef short bf16x8 __attribute__((ext_vector_type(8)));
typedef float f32x4  __attribute__((ext_vector_type(4)));

// bf16 helpers (manual, RNE pack)
__device__ __forceinline__ unsigned short f2bf(float f) {
    unsigned u = __builtin_bit_cast(unsigned, f);
    u += 0x7FFF + ((u >> 16) & 1);
    return (unsigned short)(u >> 16);
}
__device__ __forceinline__ float bflo(unsigned v) {
    return __builtin_bit_cast(float, v << 16);
}
__device__ __forceinline__ float bfhi(unsigned v) {
    return __builtin_bit_cast(float, v & 0xFFFF0000u);
}
__device__ __forceinline__ unsigned pk2(float lo, float hi) {
    return (unsigned)f2bf(lo) | ((unsigned)f2bf(hi) << 16);
}
// unpack-accumulate 8 bf16 lanes of a uint4 into acc[0..7]
__device__ __forceinline__ void accv8(float* acc, const uint4& v, float wt) {
    acc[0] += wt * bflo(v.x); acc[1] += wt * bfhi(v.x);
    acc[2] += wt * bflo(v.y); acc[3] += wt * bfhi(v.y);
    acc[4] += wt * bflo(v.z); acc[5] += wt * bfhi(v.z);
    acc[6] += wt * bflo(v.w); acc[7] += wt * bfhi(v.w);
}

// ---------------- edge-index width handling ----------------
__global__ __launch_bounds__(256)
void k_detect(const int* __restrict__ ei, int* __restrict__ mode)
{
    int k = blockIdx.x * 256 + threadIdx.x;
    if (ei[2 * k + 1] != 0) atomicOr(mode, 1);  // 1 => int32 layout
}

__device__ __forceinline__ int edge_src(const int* ei, int m, int e) {
    return m ? ei[e] : ei[2 * e];
}
__device__ __forceinline__ int edge_dst(const int* ei, int m, int e) {
    return m ? ei[NE + e] : ei[2 * (NE + e)];
}

// hist + weight packs:
//   blocks 0..47:  wAb[(kk*64+o)*64+i] = bf16 w[o][i][kk]     (conv A-layout)
//   blocks 48..95: twB[m][g*64+k]      = bf16 tw[m][k][g]     (tag B-layout, W^T)
__global__ __launch_bounds__(256)
void k_hist(const int* __restrict__ ei, const int* __restrict__ mode,
            int* __restrict__ hist, const float* __restrict__ cw,
            unsigned short* __restrict__ wAb, const float* __restrict__ tw,
            unsigned short* __restrict__ twB)
{
    int e = blockIdx.x * 256 + threadIdx.x;
    int m = *mode;
    atomicAdd(&hist[edge_dst(ei, m, e)], 1);
    if (blockIdx.x < 48) {
        int idx = e;                      // 0..12287
        int kk = idx >> 12, o = (idx >> 6) & 63, i = idx & 63;
        wAb[idx] = f2bf(cw[o * 192 + i * 3 + kk]);
    } else if (blockIdx.x < 96) {
        int idx = e - 48 * 256;           // 0..12287
        int mm = idx >> 12, rem = idx & 4095;
        int g = rem >> 6, k = rem & 63;
        twB[idx] = f2bf(tw[mm * 4096 + k * 64 + g]);
    }
}

// single block: CSR row-pointer scan
__global__ __launch_bounds__(256)
void k_scan(const int* __restrict__ hist, int* __restrict__ rowp, int* __restrict__ cur)
{
    __shared__ int part[256];
    int j = threadIdx.x;
    int loc[8]; int s = 0;
#pragma unroll
    for (int r = 0; r < 8; ++r) { loc[r] = hist[j * 8 + r]; s += loc[r]; }
    part[j] = s;
    __syncthreads();
    for (int off = 1; off < 256; off <<= 1) {
        int v = (j >= off) ? part[j - off] : 0;
        __syncthreads();
        part[j] += v;
        __syncthreads();
    }
    int excl = part[j] - s;
#pragma unroll
    for (int r = 0; r < 8; ++r) {
        rowp[j * 8 + r] = excl;
        cur [j * 8 + r] = excl;
        excl += loc[r];
    }
    if (j == 255) rowp[2048] = excl;  // == NE
}

__global__ __launch_bounds__(256)
void k_scat(const int* __restrict__ ei, const float* __restrict__ ew,
            const int* __restrict__ mode, int* __restrict__ cur,
            int* __restrict__ csrs, float* __restrict__ csrw)
{
    int e = blockIdx.x * 256 + threadIdx.x;
    int m = *mode;
    int d = edge_dst(ei, m, e);
    int pos = atomicAdd(&cur[d], 1);
    csrs[pos] = edge_src(ei, m, e);
    csrw[pos] = ew[e];
}

// ---------------- conv1d (MFMA) + leaky + LayerNorm + BN partials ----------
// (R10 body verbatim — passed, layouts validated)
__global__ __launch_bounds__(256, 8)
void k_convln(const float* __restrict__ x, const unsigned short* __restrict__ wAb,
              const float* __restrict__ cb, const float* __restrict__ lg,
              const float* __restrict__ lb, float* __restrict__ h_in,
              float* __restrict__ partials)
{
    __shared__ __align__(16) unsigned short xT[36 * 72];
    __shared__ float red1[64], red2[64];
    __shared__ float wsum[8];
    __shared__ float bcast[2];

    const int b = blockIdx.x, j = threadIdx.x;
    const float* __restrict__ xg = x + (size_t)b * NTC;

    {   // stage x -> bf16 xT[t+2][i]; zero-pad rows 0,1,34,35
        unsigned* xTd = (unsigned*)xT;
        int t = j & 31, p = j >> 5;
#pragma unroll
        for (int r = 0; r < 4; ++r) {
            int i0 = (r * 8 + p) * 2;
            float v0 = xg[i0 * 32 + t];
            float v1 = xg[(i0 + 1) * 32 + t];
            xTd[(t + 2) * 36 + (i0 >> 1)] = pk2(v0, v1);
        }
        if (j < 72)       xTd[j] = 0u;
        else if (j < 144) xTd[1224 + (j - 72)] = 0u;   // rows 34,35
    }
    if (j < 64) { red1[j] = 0.f; red2[j] = 0.f; }
    __syncthreads();

    const int lane = j & 63, w = j >> 6;
    const int n16 = lane & 15, quad = lane >> 4;

    bf16x8 afr[3][2];
#pragma unroll
    for (int kk = 0; kk < 3; ++kk)
#pragma unroll
        for (int s = 0; s < 2; ++s) {
            int off16 = (kk * 64 + w * 16 + n16) * 64 + s * 32 + quad * 8;
            afr[kk][s] = *(const bf16x8*)(wAb + off16);
        }

    f32x4 acc0 = {0.f, 0.f, 0.f, 0.f};
    f32x4 acc1 = {0.f, 0.f, 0.f, 0.f};
#pragma unroll
    for (int kk = 0; kk < 3; ++kk)
#pragma unroll
        for (int s = 0; s < 2; ++s) {
            bf16x8 b0 = *(const bf16x8*)(xT + (n16 + kk) * 72 + s * 32 + quad * 8);
            bf16x8 b1 = *(const bf16x8*)(xT + (16 + n16 + kk) * 72 + s * 32 + quad * 8);
            acc0 = __builtin_amdgcn_mfma_f32_16x16x32_bf16(afr[kk][s], b0, acc0, 0, 0, 0);
            acc1 = __builtin_amdgcn_mfma_f32_16x16x32_bf16(afr[kk][s], b1, acc1, 0, 0, 0);
        }

    float vals[2][4];
    float s1 = 0.f, s2 = 0.f;
#pragma unroll
    for (int r = 0; r < 4; ++r) {
        float cbv = cb[w * 16 + quad * 4 + r];
        float v0 = acc0[r] + cbv;
        float v1 = acc1[r] + cbv;
        v0 = (v0 >= 0.f) ? v0 : SLOPE_F * v0;
        v1 = (v1 >= 0.f) ? v1 : SLOPE_F * v1;
        vals[0][r] = v0; vals[1][r] = v1;
        s1 += v0 + v1; s2 += v0 * v0 + v1 * v1;
    }
#pragma unroll
    for (int off = 32; off > 0; off >>= 1) {
        s1 += __shfl_down(s1, off, 64);
        s2 += __shfl_down(s2, off, 64);
    }
    if (lane == 0) { wsum[w] = s1; wsum[4 + w] = s2; }
    __syncthreads();
    if (j == 0) {
        float S1 = wsum[0] + wsum[1] + wsum[2] + wsum[3];
        float S2 = wsum[4] + wsum[5] + wsum[6] + wsum[7];
        float mu  = S1 * (1.f / 2048.f);
        float var = S2 * (1.f / 2048.f) - mu * mu;
        bcast[0] = mu;
        bcast[1] = rsqrtf(var + EPS_F);
    }
    __syncthreads();
    const float mu = bcast[0], rs = bcast[1];
    float* hb = h_in + (size_t)b * NTC;
    float po1[4] = {0.f, 0.f, 0.f, 0.f}, po2[4] = {0.f, 0.f, 0.f, 0.f};
#pragma unroll
    for (int nt = 0; nt < 2; ++nt) {
        int t = nt * 16 + n16;
#pragma unroll
        for (int r = 0; r < 4; ++r) {
            int o = w * 16 + quad * 4 + r;
            float h = (vals[nt][r] - mu) * rs * lg[o * 32 + t] + lb[o * 32 + t];
            hb[t * 64 + o] = h;
            po1[r] += h; po2[r] += h * h;
        }
    }
#pragma unroll
    for (int r = 0; r < 4; ++r) {
        int o = w * 16 + quad * 4 + r;
        atomicAdd(&red1[o], po1[r]);
        atomicAdd(&red2[o], po2[r]);
    }
    __syncthreads();
    float* pb_ = partials + (size_t)b * 128;
    if (j < 64)       pb_[j] = red1[j];
    else if (j < 128) pb_[j] = red2[j - 64];
}

// ---------------- reduce partials -> BN scale/shift ----------------
__global__ __launch_bounds__(256)
void k_bnred(const float* __restrict__ partials, const float* __restrict__ bg,
             const float* __restrict__ bb, float* __restrict__ stats)
{
    const int c = blockIdx.x, j = threadIdx.x;
    float s1 = 0.f, s2 = 0.f;
    for (int b = j; b < NB; b += 256) {
        const float* p = partials + (size_t)b * 128;
        s1 += p[c];
        s2 += p[64 + c];
    }
    __shared__ float r1[4], r2[4];
#pragma unroll
    for (int off = 32; off > 0; off >>= 1) {
        s1 += __shfl_down(s1, off, 64);
        s2 += __shfl_down(s2, off, 64);
    }
    if ((j & 63) == 0) { r1[j >> 6] = s1; r2[j >> 6] = s2; }
    __syncthreads();
    if (j == 0) {
        float S1 = r1[0] + r1[1] + r1[2] + r1[3];
        float S2 = r2[0] + r2[1] + r2[2] + r2[3];
        const float inv_n = 1.f / 65536.f;
        float mu  = S1 * inv_n;
        float var = S2 * inv_n - mu * mu;
        float rs  = rsqrtf(var + EPS_F);
        float sc  = bg[c] * rs;
        stats[128 + c] = sc;
        stats[192 + c] = bb[c] - mu * sc;
    }
}

// ---------------- z = leaky(BN(h)); out = h + z@W0 + tag_b (MFMA) ----------
// z@W0 as M32(t) x K64(f) x N64(g) MFMA: A = bf16 zA[t][f] in LDS (4KB),
// B = bf16 W^T[g][k] per-lane coalesced from global. D gives 4 consecutive t
// at fixed g -> float4 stores into out[b][g][t].
__global__ __launch_bounds__(256, 8)
void k_zw0(const float* __restrict__ h_in, const float* __restrict__ stats,
           const unsigned short* __restrict__ twB, const float* __restrict__ tb,
           unsigned short* __restrict__ zb16, float* __restrict__ out)
{
    __shared__ __align__(16) unsigned short zA[32 * 64];  // bf16 z, 128B rows
    __shared__ float hl[32 * 65];                          // fp32 h residual
    const int b = blockIdx.x, j = threadIdx.x;
    const int c = j & 63;
    const float sc = stats[128 + c], sh = stats[192 + c];
    const float* hb = h_in + (size_t)b * NTC;
    unsigned short* zb = zb16 + (size_t)b * NTC;
#pragma unroll
    for (int r = 0; r < 8; ++r) {
        int idx = j + r * 256;                    // idx = t*64 + c
        int t = idx >> 6;
        float h = hb[idx];
        float zv = h * sc + sh;
        zv = (zv >= 0.f) ? zv : SLOPE_F * zv;
        unsigned short zh = f2bf(zv);
        zb[idx] = zh;                             // bf16 payload for hop1
        zA[idx] = zh;                             // same layout t*64+c
        hl[t * 65 + c] = h;
    }
    __syncthreads();
    const int lane = j & 63, w = j >> 6;
    const int n16 = lane & 15, quad = lane >> 4;
    const int g = w * 16 + n16;

    bf16x8 a00 = *(const bf16x8*)(zA + (n16)      * 64 +      quad * 8);
    bf16x8 a01 = *(const bf16x8*)(zA + (n16)      * 64 + 32 + quad * 8);
    bf16x8 a10 = *(const bf16x8*)(zA + (16 + n16) * 64 +      quad * 8);
    bf16x8 a11 = *(const bf16x8*)(zA + (16 + n16) * 64 + 32 + quad * 8);
    bf16x8 b0  = *(const bf16x8*)(twB + g * 64 +      quad * 8);
    bf16x8 b1  = *(const bf16x8*)(twB + g * 64 + 32 + quad * 8);

    f32x4 d0 = {0.f, 0.f, 0.f, 0.f};
    f32x4 d1 = {0.f, 0.f, 0.f, 0.f};
    d0 = __builtin_amdgcn_mfma_f32_16x16x32_bf16(a00, b0, d0, 0, 0, 0);
    d0 = __builtin_amdgcn_mfma_f32_16x16x32_bf16(a01, b1, d0, 0, 0, 0);
    d1 = __builtin_amdgcn_mfma_f32_16x16x32_bf16(a10, b0, d1, 0, 0, 0);
    d1 = __builtin_amdgcn_mfma_f32_16x16x32_bf16(a11, b1, d1, 0, 0, 0);

    const float tbg = tb[g];
    float* ob = out + (size_t)b * NTC + g * 32;   // out[b][g][t]
    {
        float4 v;                                  // mtile 0: t = quad*4..+3
        v.x = d0[0] + tbg + hl[(quad * 4 + 0) * 65 + g];
        v.y = d0[1] + tbg + hl[(quad * 4 + 1) * 65 + g];
        v.z = d0[2] + tbg + hl[(quad * 4 + 2) * 65 + g];
        v.w = d0[3] + tbg + hl[(quad * 4 + 3) * 65 + g];
        *(float4*)(ob + quad * 4) = v;
    }
    {
        float4 v;                                  // mtile 1: t = 16+quad*4..+3
        v.x = d1[0] + tbg + hl[(16 + quad * 4 + 0) * 65 + g];
        v.y = d1[1] + tbg + hl[(16 + quad * 4 + 1) * 65 + g];
        v.z = d1[2] + tbg + hl[(16 + quad * 4 + 2) * 65 + g];
        v.w = d1[3] + tbg + hl[(16 + quad * 4 + 3) * 65 + g];
        *(float4*)(ob + 16 + quad * 4) = v;
    }
}

// ---------------- one propagation hop (bf16 gather) + MFMA matmul ----------
__global__ __launch_bounds__(256, 8)
void k_hop(const unsigned short* __restrict__ p_in, const int* __restrict__ rowp,
           const int* __restrict__ csrs, const float* __restrict__ csrw,
           const unsigned short* __restrict__ twB, unsigned short* __restrict__ p_out,
           float* __restrict__ out)
{
    __shared__ __align__(16) unsigned short pA[32 * 64];   // bf16 p_next, 4KB
    const int d = blockIdx.x, j = threadIdx.x;
    const int beg = rowp[d], end = rowp[d + 1];
    float acc[8];
#pragma unroll
    for (int r = 0; r < 8; ++r) acc[r] = 0.f;
    int e = beg;
    for (; e + 4 <= end; e += 4) {                // 4 gathers in flight
        int s0 = csrs[e],  s1 = csrs[e+1], s2 = csrs[e+2], s3 = csrs[e+3];
        float w0 = csrw[e], w1 = csrw[e+1], w2 = csrw[e+2], w3 = csrw[e+3];
        uint4 v0 = ((const uint4*)(p_in + (size_t)s0 * NTC))[j];  // 16B = 8 bf16
        uint4 v1 = ((const uint4*)(p_in + (size_t)s1 * NTC))[j];
        uint4 v2 = ((const uint4*)(p_in + (size_t)s2 * NTC))[j];
        uint4 v3 = ((const uint4*)(p_in + (size_t)s3 * NTC))[j];
        accv8(acc, v0, w0); accv8(acc, v1, w1);
        accv8(acc, v2, w2); accv8(acc, v3, w3);
    }
    for (; e < end; ++e) {
        int s0 = csrs[e];
        float w0 = csrw[e];
        uint4 v0 = ((const uint4*)(p_in + (size_t)s0 * NTC))[j];
        accv8(acc, v0, w0);
    }
    uint4 pv;                                     // thread j owns elems j*8..+7
    pv.x = pk2(acc[0], acc[1]); pv.y = pk2(acc[2], acc[3]);
    pv.z = pk2(acc[4], acc[5]); pv.w = pk2(acc[6], acc[7]);
    if (p_out)
        ((uint4*)(p_out + (size_t)d * NTC))[j] = pv;
    ((uint4*)pA)[j] = pv;                         // pA[t][c], t=j>>3, c0=(j&7)*8
    __syncthreads();

    const int lane = j & 63, w = j >> 6;
    const int n16 = lane & 15, quad = lane >> 4;
    const int g = w * 16 + n16;

    bf16x8 a00 = *(const bf16x8*)(pA + (n16)      * 64 +      quad * 8);
    bf16x8 a01 = *(const bf16x8*)(pA + (n16)      * 64 + 32 + quad * 8);
    bf16x8 a10 = *(const bf16x8*)(pA + (16 + n16) * 64 +      quad * 8);
    bf16x8 a11 = *(const bf16x8*)(pA + (16 + n16) * 64 + 32 + quad * 8);
    bf16x8 b0  = *(const bf16x8*)(twB + g * 64 +      quad * 8);
    bf16x8 b1  = *(const bf16x8*)(twB + g * 64 + 32 + quad * 8);

    f32x4 d0 = {0.f, 0.f, 0.f, 0.f};
    f32x4 d1 = {0.f, 0.f, 0.f, 0.f};
    d0 = __builtin_amdgcn_mfma_f32_16x16x32_bf16(a00, b0, d0, 0, 0, 0);
    d0 = __builtin_amdgcn_mfma_f32_16x16x32_bf16(a01, b1, d0, 0, 0, 0);
    d1 = __builtin_amdgcn_mfma_f32_16x16x32_bf16(a10, b0, d1, 0, 0, 0);
    d1 = __builtin_amdgcn_mfma_f32_16x16x32_bf16(a11, b1, d1, 0, 0, 0);

    float* ob = out + (size_t)d * NTC + g * 32;   // out[b][g][t], block owns d
    {
        float4 v = *(float4*)(ob + quad * 4);
        v.x += d0[0]; v.y += d0[1]; v.z += d0[2]; v.w += d0[3];
        *(float4*)(ob + quad * 4) = v;
    }
    {
        float4 v = *(float4*)(ob + 16 + quad * 4);
        v.x += d1[0]; v.y += d1[1]; v.z += d1[2]; v.w += d1[3];
        *(float4*)(ob + 16 + quad * 4) = v;
    }
}

// ---------------- launch ----------------
// workspace floats:
//   [0, 4194304)        h_in [b][t][c] fp32
//   [4194304, 6291456)  z_bf16  [b][t][c] (ushort, 8MB)
//   [6291456, 8388608)  p1_bf16 [b][t][c] (ushort, 8MB)
//   [8388608, +256)     stats (scale[64]@128, shift[64]@192)
//   [8388864, +6144)    wAb (bf16 conv A-layout, 24KB)
//   [8395008, +6144)    twB (bf16 tag W^T B-layout, 24KB)
//   [8405248, +262144)  partials [b][128]
//   [8667392, ...)      ints: mode(4) hist(2048) rowp(2052) cur(2048)
//                             csrs(32768) csrw(32768)        (~35 MiB total)
extern "C" void kernel_launch(void* const* d_in, const int* in_sizes, int n_in,
                              void* d_out, int out_size, void* d_ws, size_t ws_size,
                              hipStream_t stream)
{
    const float* x  = (const float*)d_in[0];
    const int*   ei = (const int*)  d_in[1];
    const float* ew = (const float*)d_in[2];
    const float* cw = (const float*)d_in[3];
    const float* cb = (const float*)d_in[4];
    const float* lg = (const float*)d_in[5];
    const float* lb = (const float*)d_in[6];
    const float* bg = (const float*)d_in[7];
    const float* bb = (const float*)d_in[8];
    const float* tw = (const float*)d_in[9];
    const float* tb = (const float*)d_in[10];
    float* out = (float*)d_out;
    float* ws  = (float*)d_ws;

    float*          h_in  = ws;
    unsigned short* zbf   = (unsigned short*)(ws + 4194304);
    unsigned short* p1bf  = (unsigned short*)(ws + 6291456);
    float*          stats = ws + 8388608;
    unsigned short* wAb   = (unsigned short*)(ws + 8388864);
    unsigned short* twB   = (unsigned short*)(ws + 8395008);
    float*          parts = ws + 8405248;
    int*            ib    = (int*)(ws + 8667392);
    int*   mode  = ib;
    int*   hist  = ib + 4;
    int*   rowp  = ib + 2052;
    int*   cur   = ib + 4104;
    int*   csrs  = ib + 6152;
    float* csrw  = (float*)(ib + 38920);

    (void)hipMemsetAsync(ib, 0, 2052 * sizeof(int), stream);   // mode + hist

    k_detect <<<128, 256, 0, stream>>>(ei, mode);
    k_hist   <<<128, 256, 0, stream>>>(ei, mode, hist, cw, wAb, tw, twB);
    k_scan   <<<1,   256, 0, stream>>>(hist, rowp, cur);
    k_scat   <<<128, 256, 0, stream>>>(ei, ew, mode, cur, csrs, csrw);
    k_convln <<<NB,  256, 0, stream>>>(x, wAb, cb, lg, lb, h_in, parts);
    k_bnred  <<<64,  256, 0, stream>>>(parts, bg, bb, stats);
    k_zw0    <<<NB,  256, 0, stream>>>(h_in, stats, twB, tb, zbf, out);
    k_hop    <<<NB,  256, 0, stream>>>(zbf,  rowp, csrs, csrw, twB + 4096, p1bf, out);
    k_hop    <<<NB,  256, 0, stream>>>(p1bf, rowp, csrs, csrw, twB + 8192, nullptr, out);
}

// Round 13
// 196.293 us; speedup vs baseline: 1.5749x; 1.0119x over previous
//
#include <hip/hip_runtime.h>
#include <cstddef>

// B=2048, C_IN=C_OUT=64, T=32, E=32768, K_HOPS=2, KSIZE=3
#define NB   2048
#define NE   32768
#define NTC  2048      // T*C elems per node
#define SLOPE_F 0.01f
#define EPS_F   1e-5f

typedef short bf16x8 __attribute__((ext_vector_type(8)));
typedef float f32x4  __attribute__((ext_vector_type(4)));

// bf16 helpers (manual, RNE pack)
__device__ __forceinline__ unsigned short f2bf(float f) {
    unsigned u = __builtin_bit_cast(unsigned, f);
    u += 0x7FFF + ((u >> 16) & 1);
    return (unsigned short)(u >> 16);
}
__device__ __forceinline__ float bflo(unsigned v) {
    return __builtin_bit_cast(float, v << 16);
}
__device__ __forceinline__ float bfhi(unsigned v) {
    return __builtin_bit_cast(float, v & 0xFFFF0000u);
}
__device__ __forceinline__ unsigned pk2(float lo, float hi) {
    return (unsigned)f2bf(lo) | ((unsigned)f2bf(hi) << 16);
}
// unpack-accumulate 8 bf16 lanes of a uint4 into acc[0..7]
__device__ __forceinline__ void accv8(float* acc, const uint4& v, float wt) {
    acc[0] += wt * bflo(v.x); acc[1] += wt * bfhi(v.x);
    acc[2] += wt * bflo(v.y); acc[3] += wt * bfhi(v.y);
    acc[4] += wt * bflo(v.z); acc[5] += wt * bfhi(v.z);
    acc[6] += wt * bflo(v.w); acc[7] += wt * bfhi(v.w);
}

// ---------------- edge-index width handling ----------------
__global__ __launch_bounds__(256)
void k_detect(const int* __restrict__ ei, int* __restrict__ mode)
{
    int k = blockIdx.x * 256 + threadIdx.x;
    if (ei[2 * k + 1] != 0) atomicOr(mode, 1);  // 1 => int32 layout
}

__device__ __forceinline__ int edge_src(const int* ei, int m, int e) {
    return m ? ei[e] : ei[2 * e];
}
__device__ __forceinline__ int edge_dst(const int* ei, int m, int e) {
    return m ? ei[NE + e] : ei[2 * (NE + e)];
}

// hist + weight packs:
//   blocks 0..47:  wAb[(kk*64+o)*64+i] = bf16 w[o][i][kk]     (conv A-layout)
//   blocks 48..95: twB[m][g*64+k]      = bf16 tw[m][k][g]     (tag B-layout, W^T)
__global__ __launch_bounds__(256)
void k_hist(const int* __restrict__ ei, const int* __restrict__ mode,
            int* __restrict__ hist, const float* __restrict__ cw,
            unsigned short* __restrict__ wAb, const float* __restrict__ tw,
            unsigned short* __restrict__ twB)
{
    int e = blockIdx.x * 256 + threadIdx.x;
    int m = *mode;
    atomicAdd(&hist[edge_dst(ei, m, e)], 1);
    if (blockIdx.x < 48) {
        int idx = e;                      // 0..12287
        int kk = idx >> 12, o = (idx >> 6) & 63, i = idx & 63;
        wAb[idx] = f2bf(cw[o * 192 + i * 3 + kk]);
    } else if (blockIdx.x < 96) {
        int idx = e - 48 * 256;           // 0..12287
        int mm = idx >> 12, rem = idx & 4095;
        int g = rem >> 6, k = rem & 63;
        twB[idx] = f2bf(tw[mm * 4096 + k * 64 + g]);
    }
}

// single block: CSR row-pointer scan
__global__ __launch_bounds__(256)
void k_scan(const int* __restrict__ hist, int* __restrict__ rowp, int* __restrict__ cur)
{
    __shared__ int part[256];
    int j = threadIdx.x;
    int loc[8]; int s = 0;
#pragma unroll
    for (int r = 0; r < 8; ++r) { loc[r] = hist[j * 8 + r]; s += loc[r]; }
    part[j] = s;
    __syncthreads();
    for (int off = 1; off < 256; off <<= 1) {
        int v = (j >= off) ? part[j - off] : 0;
        __syncthreads();
        part[j] += v;
        __syncthreads();
    }
    int excl = part[j] - s;
#pragma unroll
    for (int r = 0; r < 8; ++r) {
        rowp[j * 8 + r] = excl;
        cur [j * 8 + r] = excl;
        excl += loc[r];
    }
    if (j == 255) rowp[2048] = excl;  // == NE
}

__global__ __launch_bounds__(256)
void k_scat(const int* __restrict__ ei, const float* __restrict__ ew,
            const int* __restrict__ mode, int* __restrict__ cur,
            int* __restrict__ csrs, float* __restrict__ csrw)
{
    int e = blockIdx.x * 256 + threadIdx.x;
    int m = *mode;
    int d = edge_dst(ei, m, e);
    int pos = atomicAdd(&cur[d], 1);
    csrs[pos] = edge_src(ei, m, e);
    csrw[pos] = ew[e];
}

// ---------------- conv1d (MFMA) + leaky + LayerNorm + BN partials ----------
// R12 body (fast: no spills, coalesced h-store via LDS bounce, shuffle BN)
__global__ __launch_bounds__(256, 4)
void k_convln(const float* __restrict__ x, const unsigned short* __restrict__ wAb,
              const float* __restrict__ cb, const float* __restrict__ lg,
              const float* __restrict__ lb, float* __restrict__ h_in,
              float* __restrict__ partials)
{
    __shared__ __align__(16) unsigned short xT[36 * 72];
    __shared__ float hT[32 * 65];
    __shared__ float red1[64], red2[64];
    __shared__ float wsum[8];
    __shared__ float bcast[2];

    const int b = blockIdx.x, j = threadIdx.x;
    const float* __restrict__ xg = x + (size_t)b * NTC;

    {   // stage x -> bf16 xT[t+2][i]; zero-pad rows 0,1,34,35
        unsigned* xTd = (unsigned*)xT;
        int t = j & 31, p = j >> 5;
#pragma unroll
        for (int r = 0; r < 4; ++r) {
            int i0 = (r * 8 + p) * 2;
            float v0 = xg[i0 * 32 + t];
            float v1 = xg[(i0 + 1) * 32 + t];
            xTd[(t + 2) * 36 + (i0 >> 1)] = pk2(v0, v1);
        }
        if (j < 72)       xTd[j] = 0u;
        else if (j < 144) xTd[1224 + (j - 72)] = 0u;   // rows 34,35
    }
    __syncthreads();

    const int lane = j & 63, w = j >> 6;
    const int n16 = lane & 15, quad = lane >> 4;

    bf16x8 afr[3][2];
#pragma unroll
    for (int kk = 0; kk < 3; ++kk)
#pragma unroll
        for (int s = 0; s < 2; ++s) {
            int off16 = (kk * 64 + w * 16 + n16) * 64 + s * 32 + quad * 8;
            afr[kk][s] = *(const bf16x8*)(wAb + off16);
        }

    f32x4 acc0 = {0.f, 0.f, 0.f, 0.f};
    f32x4 acc1 = {0.f, 0.f, 0.f, 0.f};
#pragma unroll
    for (int kk = 0; kk < 3; ++kk)
#pragma unroll
        for (int s = 0; s < 2; ++s) {
            bf16x8 b0 = *(const bf16x8*)(xT + (n16 + kk) * 72 + s * 32 + quad * 8);
            bf16x8 b1 = *(const bf16x8*)(xT + (16 + n16 + kk) * 72 + s * 32 + quad * 8);
            acc0 = __builtin_amdgcn_mfma_f32_16x16x32_bf16(afr[kk][s], b0, acc0, 0, 0, 0);
            acc1 = __builtin_amdgcn_mfma_f32_16x16x32_bf16(afr[kk][s], b1, acc1, 0, 0, 0);
        }

    float vals[2][4];
    float s1 = 0.f, s2 = 0.f;
#pragma unroll
    for (int r = 0; r < 4; ++r) {
        float cbv = cb[w * 16 + quad * 4 + r];
        float v0 = acc0[r] + cbv;
        float v1 = acc1[r] + cbv;
        v0 = (v0 >= 0.f) ? v0 : SLOPE_F * v0;
        v1 = (v1 >= 0.f) ? v1 : SLOPE_F * v1;
        vals[0][r] = v0; vals[1][r] = v1;
        s1 += v0 + v1; s2 += v0 * v0 + v1 * v1;
    }
#pragma unroll
    for (int off = 32; off > 0; off >>= 1) {
        s1 += __shfl_down(s1, off, 64);
        s2 += __shfl_down(s2, off, 64);
    }
    if (lane == 0) { wsum[w] = s1; wsum[4 + w] = s2; }
    __syncthreads();
    if (j == 0) {
        float S1 = wsum[0] + wsum[1] + wsum[2] + wsum[3];
        float S2 = wsum[4] + wsum[5] + wsum[6] + wsum[7];
        float mu  = S1 * (1.f / 2048.f);
        float var = S2 * (1.f / 2048.f) - mu * mu;
        bcast[0] = mu;
        bcast[1] = rsqrtf(var + EPS_F);
    }
    __syncthreads();
    const float mu = bcast[0], rs = bcast[1];
    float po1[4] = {0.f, 0.f, 0.f, 0.f}, po2[4] = {0.f, 0.f, 0.f, 0.f};
#pragma unroll
    for (int nt = 0; nt < 2; ++nt) {
        int t = nt * 16 + n16;
#pragma unroll
        for (int r = 0; r < 4; ++r) {
            int o = w * 16 + quad * 4 + r;
            float h = (vals[nt][r] - mu) * rs * lg[o * 32 + t] + lb[o * 32 + t];
            hT[t * 65 + o] = h;
            po1[r] += h; po2[r] += h * h;
        }
    }
#pragma unroll
    for (int off = 8; off > 0; off >>= 1) {
#pragma unroll
        for (int r = 0; r < 4; ++r) {
            po1[r] += __shfl_down(po1[r], off, 16);
            po2[r] += __shfl_down(po2[r], off, 16);
        }
    }
    if (n16 == 0) {
#pragma unroll
        for (int r = 0; r < 4; ++r) {
            int o = w * 16 + quad * 4 + r;
            red1[o] = po1[r];
            red2[o] = po2[r];
        }
    }
    __syncthreads();
    float* hb = h_in + (size_t)b * NTC;
#pragma unroll
    for (int r = 0; r < 8; ++r) {                  // coalesced h_in store
        int idx = j + r * 256;
        hb[idx] = hT[(idx >> 6) * 65 + (idx & 63)];
    }
    float* pb_ = partials + (size_t)b * 128;       // coalesced 512B store
    if (j < 64)       pb_[j] = red1[j];
    else if (j < 128) pb_[j] = red2[j - 64];
}

// ---------------- reduce partials -> BN scale/shift ----------------
__global__ __launch_bounds__(256)
void k_bnred(const float* __restrict__ partials, const float* __restrict__ bg,
             const float* __restrict__ bb, float* __restrict__ stats)
{
    const int c = blockIdx.x, j = threadIdx.x;
    float s1 = 0.f, s2 = 0.f;
    for (int b = j; b < NB; b += 256) {
        const float* p = partials + (size_t)b * 128;
        s1 += p[c];
        s2 += p[64 + c];
    }
    __shared__ float r1[4], r2[4];
#pragma unroll
    for (int off = 32; off > 0; off >>= 1) {
        s1 += __shfl_down(s1, off, 64);
        s2 += __shfl_down(s2, off, 64);
    }
    if ((j & 63) == 0) { r1[j >> 6] = s1; r2[j >> 6] = s2; }
    __syncthreads();
    if (j == 0) {
        float S1 = r1[0] + r1[1] + r1[2] + r1[3];
        float S2 = r2[0] + r2[1] + r2[2] + r2[3];
        const float inv_n = 1.f / 65536.f;
        float mu  = S1 * inv_n;
        float var = S2 * inv_n - mu * mu;
        float rs  = rsqrtf(var + EPS_F);
        float sc  = bg[c] * rs;
        stats[128 + c] = sc;
        stats[192 + c] = bb[c] - mu * sc;
    }
}

// ---------------- z = leaky(BN(h)); out = h + z@W0 + tag_b (MFMA) ----------
// z has magnitude ~1 -> bf16 error here is negligible.
__global__ __launch_bounds__(256, 6)
void k_zw0(const float* __restrict__ h_in, const float* __restrict__ stats,
           const unsigned short* __restrict__ twB, const float* __restrict__ tb,
           unsigned short* __restrict__ zb16, float* __restrict__ out)
{
    __shared__ __align__(16) unsigned short zA[32 * 64];  // bf16 z, 4KB
    __shared__ float hl[32 * 65];                          // fp32 h residual
    const int b = blockIdx.x, j = threadIdx.x;
    const int c = j & 63;
    const float sc = stats[128 + c], sh = stats[192 + c];
    const float* hb = h_in + (size_t)b * NTC;
    unsigned short* zb = zb16 + (size_t)b * NTC;
#pragma unroll
    for (int r = 0; r < 8; ++r) {
        int idx = j + r * 256;                    // idx = t*64 + c
        int t = idx >> 6;
        float h = hb[idx];
        float zv = h * sc + sh;
        zv = (zv >= 0.f) ? zv : SLOPE_F * zv;
        unsigned short zh = f2bf(zv);
        zb[idx] = zh;                             // bf16 payload for hop1
        zA[idx] = zh;                             // same layout t*64+c
        hl[t * 65 + c] = h;
    }
    __syncthreads();
    const int lane = j & 63, w = j >> 6;
    const int n16 = lane & 15, quad = lane >> 4;
    const int g = w * 16 + n16;

    bf16x8 a00 = *(const bf16x8*)(zA + (n16)      * 64 +      quad * 8);
    bf16x8 a01 = *(const bf16x8*)(zA + (n16)      * 64 + 32 + quad * 8);
    bf16x8 a10 = *(const bf16x8*)(zA + (16 + n16) * 64 +      quad * 8);
    bf16x8 a11 = *(const bf16x8*)(zA + (16 + n16) * 64 + 32 + quad * 8);
    bf16x8 b0  = *(const bf16x8*)(twB + g * 64 +      quad * 8);
    bf16x8 b1  = *(const bf16x8*)(twB + g * 64 + 32 + quad * 8);

    f32x4 d0 = {0.f, 0.f, 0.f, 0.f};
    f32x4 d1 = {0.f, 0.f, 0.f, 0.f};
    d0 = __builtin_amdgcn_mfma_f32_16x16x32_bf16(a00, b0, d0, 0, 0, 0);
    d0 = __builtin_amdgcn_mfma_f32_16x16x32_bf16(a01, b1, d0, 0, 0, 0);
    d1 = __builtin_amdgcn_mfma_f32_16x16x32_bf16(a10, b0, d1, 0, 0, 0);
    d1 = __builtin_amdgcn_mfma_f32_16x16x32_bf16(a11, b1, d1, 0, 0, 0);

    const float tbg = tb[g];
    float* ob = out + (size_t)b * NTC + g * 32;   // out[b][g][t]
    {
        float4 v;                                  // mtile 0: t = quad*4..+3
        v.x = d0[0] + tbg + hl[(quad * 4 + 0) * 65 + g];
        v.y = d0[1] + tbg + hl[(quad * 4 + 1) * 65 + g];
        v.z = d0[2] + tbg + hl[(quad * 4 + 2) * 65 + g];
        v.w = d0[3] + tbg + hl[(quad * 4 + 3) * 65 + g];
        *(float4*)(ob + quad * 4) = v;
    }
    {
        float4 v;                                  // mtile 1: t = 16+quad*4..+3
        v.x = d1[0] + tbg + hl[(16 + quad * 4 + 0) * 65 + g];
        v.y = d1[1] + tbg + hl[(16 + quad * 4 + 1) * 65 + g];
        v.z = d1[2] + tbg + hl[(16 + quad * 4 + 2) * 65 + g];
        v.w = d1[3] + tbg + hl[(16 + quad * 4 + 3) * 65 + g];
        *(float4*)(ob + 16 + quad * 4) = v;
    }
}

// ---------------- hop 1: bf16 gather of z + MFMA; p1 stored FP32 -----------
// R12 post-mortem: p1 magnitudes (~30) made the bf16 payload the first link
// of the threshold-edge error chain. Store p1 in fp32; keep bf16 only as the
// (error-tolerant) MFMA A-input.
__global__ __launch_bounds__(256, 6)
void k_hop1(const unsigned short* __restrict__ p_in, const int* __restrict__ rowp,
            const int* __restrict__ csrs, const float* __restrict__ csrw,
            const unsigned short* __restrict__ twB, float* __restrict__ p_out,
            float* __restrict__ out)
{
    __shared__ __align__(16) unsigned short pA[32 * 64];   // bf16 p1, 4KB
    const int d = blockIdx.x, j = threadIdx.x;
    const int beg = rowp[d], end = rowp[d + 1];
    float acc[8];
#pragma unroll
    for (int r = 0; r < 8; ++r) acc[r] = 0.f;
    int e = beg;
    for (; e + 4 <= end; e += 4) {                // 4 gathers in flight
        int s0 = csrs[e],  s1 = csrs[e+1], s2 = csrs[e+2], s3 = csrs[e+3];
        float w0 = csrw[e], w1 = csrw[e+1], w2 = csrw[e+2], w3 = csrw[e+3];
        uint4 v0 = ((const uint4*)(p_in + (size_t)s0 * NTC))[j];  // 16B = 8 bf16
        uint4 v1 = ((const uint4*)(p_in + (size_t)s1 * NTC))[j];
        uint4 v2 = ((const uint4*)(p_in + (size_t)s2 * NTC))[j];
        uint4 v3 = ((const uint4*)(p_in + (size_t)s3 * NTC))[j];
        accv8(acc, v0, w0); accv8(acc, v1, w1);
        accv8(acc, v2, w2); accv8(acc, v3, w3);
    }
    for (; e < end; ++e) {
        int s0 = csrs[e];
        float w0 = csrw[e];
        uint4 v0 = ((const uint4*)(p_in + (size_t)s0 * NTC))[j];
        accv8(acc, v0, w0);
    }
    {   // p1 fp32 store: thread j owns elems 8j..8j+7 of [t][c] row-major
        float4* po = (float4*)(p_out + (size_t)d * NTC);
        float4 q0 = {acc[0], acc[1], acc[2], acc[3]};
        float4 q1 = {acc[4], acc[5], acc[6], acc[7]};
        po[2 * j]     = q0;
        po[2 * j + 1] = q1;
    }
    uint4 pv;
    pv.x = pk2(acc[0], acc[1]); pv.y = pk2(acc[2], acc[3]);
    pv.z = pk2(acc[4], acc[5]); pv.w = pk2(acc[6], acc[7]);
    ((uint4*)pA)[j] = pv;                         // pA[t][c], t=j>>3
    __syncthreads();

    const int lane = j & 63, w = j >> 6;
    const int n16 = lane & 15, quad = lane >> 4;
    const int g = w * 16 + n16;

    bf16x8 a00 = *(const bf16x8*)(pA + (n16)      * 64 +      quad * 8);
    bf16x8 a01 = *(const bf16x8*)(pA + (n16)      * 64 + 32 + quad * 8);
    bf16x8 a10 = *(const bf16x8*)(pA + (16 + n16) * 64 +      quad * 8);
    bf16x8 a11 = *(const bf16x8*)(pA + (16 + n16) * 64 + 32 + quad * 8);
    bf16x8 b0  = *(const bf16x8*)(twB + g * 64 +      quad * 8);
    bf16x8 b1  = *(const bf16x8*)(twB + g * 64 + 32 + quad * 8);

    f32x4 d0 = {0.f, 0.f, 0.f, 0.f};
    f32x4 d1 = {0.f, 0.f, 0.f, 0.f};
    d0 = __builtin_amdgcn_mfma_f32_16x16x32_bf16(a00, b0, d0, 0, 0, 0);
    d0 = __builtin_amdgcn_mfma_f32_16x16x32_bf16(a01, b1, d0, 0, 0, 0);
    d1 = __builtin_amdgcn_mfma_f32_16x16x32_bf16(a10, b0, d1, 0, 0, 0);
    d1 = __builtin_amdgcn_mfma_f32_16x16x32_bf16(a11, b1, d1, 0, 0, 0);

    float* ob = out + (size_t)d * NTC + g * 32;   // out[b][g][t], block owns d
    {
        float4 v = *(float4*)(ob + quad * 4);
        v.x += d0[0]; v.y += d0[1]; v.z += d0[2]; v.w += d0[3];
        *(float4*)(ob + quad * 4) = v;
    }
    {
        float4 v = *(float4*)(ob + 16 + quad * 4);
        v.x += d1[0]; v.y += d1[1]; v.z += d1[2]; v.w += d1[3];
        *(float4*)(ob + 16 + quad * 4) = v;
    }
}

// ---------------- hop 2: FP32 gather + FP32 LDS matmul (R8 pattern) --------
// p2 magnitudes (~200-500) sit where bf16 ulp is 1-4: this stage must stay
// fp32 end-to-end (gather payload, matmul input, W2).
__global__ __launch_bounds__(256, 6)
void k_hop2(const float* __restrict__ p_in, const int* __restrict__ rowp,
            const int* __restrict__ csrs, const float* __restrict__ csrw,
            const float* __restrict__ tw, float* __restrict__ out)
{
    __shared__ float pl[32 * 65];
    __shared__ __align__(16) float W[64 * 64];
    const int d = blockIdx.x, j = threadIdx.x;
#pragma unroll
    for (int r = 0; r < 16; ++r) { int idx = j + r * 256; W[idx] = tw[idx]; }
    const int beg = rowp[d], end = rowp[d + 1];
    float acc[8];
#pragma unroll
    for (int r = 0; r < 8; ++r) acc[r] = 0.f;
    int e = beg;
    for (; e + 2 <= end; e += 2) {                // 2-edge unroll, 4 loads in flight
        int s0 = csrs[e],  s1 = csrs[e+1];
        float w0 = csrw[e], w1 = csrw[e+1];
        const float4* pb0 = (const float4*)(p_in + (size_t)s0 * NTC);
        const float4* pb1 = (const float4*)(p_in + (size_t)s1 * NTC);
        float4 a0 = pb0[2*j], a1 = pb0[2*j+1];    // elems 8j..8j+7
        float4 c0 = pb1[2*j], c1 = pb1[2*j+1];
        acc[0] += w0*a0.x; acc[1] += w0*a0.y; acc[2] += w0*a0.z; acc[3] += w0*a0.w;
        acc[4] += w0*a1.x; acc[5] += w0*a1.y; acc[6] += w0*a1.z; acc[7] += w0*a1.w;
        acc[0] += w1*c0.x; acc[1] += w1*c0.y; acc[2] += w1*c0.z; acc[3] += w1*c0.w;
        acc[4] += w1*c1.x; acc[5] += w1*c1.y; acc[6] += w1*c1.z; acc[7] += w1*c1.w;
    }
    if (e < end) {
        int s0 = csrs[e];
        float w0 = csrw[e];
        const float4* pb0 = (const float4*)(p_in + (size_t)s0 * NTC);
        float4 a0 = pb0[2*j], a1 = pb0[2*j+1];
        acc[0] += w0*a0.x; acc[1] += w0*a0.y; acc[2] += w0*a0.z; acc[3] += w0*a0.w;
        acc[4] += w0*a1.x; acc[5] += w0*a1.y; acc[6] += w0*a1.z; acc[7] += w0*a1.w;
    }
    {
        int tt = j >> 3, c0 = (j & 7) * 8;        // thread owns elems j*8..+7
        float* q = &pl[tt * 65 + c0];
#pragma unroll
        for (int s = 0; s < 8; ++s) q[s] = acc[s];
    }
    __syncthreads();
    const int t = j & 31, gq = (j >> 5) * 8;
    float accm[8];
#pragma unroll
    for (int r = 0; r < 8; ++r) accm[r] = 0.f;
    for (int f = 0; f < 64; ++f) {
        float pv = pl[t * 65 + f];
        const float4* Wr = (const float4*)&W[f * 64 + gq];
        float4 wa = Wr[0], wb = Wr[1];
        accm[0] += pv*wa.x; accm[1] += pv*wa.y; accm[2] += pv*wa.z; accm[3] += pv*wa.w;
        accm[4] += pv*wb.x; accm[5] += pv*wb.y; accm[6] += pv*wb.z; accm[7] += pv*wb.w;
    }
    float* ob = out + (size_t)d * NTC;
#pragma unroll
    for (int r = 0; r < 8; ++r)
        ob[(gq + r) * 32 + t] += accm[r];         // block owns node d: safe RMW
}

// ---------------- launch ----------------
// workspace floats:
//   [0, 4194304)          h_in [b][t][c] fp32
//   [4194304, 8388608)    p1 fp32 [b][t][c] (16MB)
//   [8388608, 10485760)   z_bf16 [b][t][c] (ushort, 8MB)
//   [10485760, +256)      stats (scale[64]@128, shift[64]@192)
//   [10486016, +6144)     wAb (bf16 conv A-layout, 24KB)
//   [10492160, +6144)     twB (bf16 tag W^T B-layout, 24KB)
//   [10498304, +262144)   partials [b][128]
//   [10760448, ...)       ints: mode(4) hist(2048) rowp(2052) cur(2048)
//                               csrs(32768) csrw(32768)      (~43 MiB total)
extern "C" void kernel_launch(void* const* d_in, const int* in_sizes, int n_in,
                              void* d_out, int out_size, void* d_ws, size_t ws_size,
                              hipStream_t stream)
{
    const float* x  = (const float*)d_in[0];
    const int*   ei = (const int*)  d_in[1];
    const float* ew = (const float*)d_in[2];
    const float* cw = (const float*)d_in[3];
    const float* cb = (const float*)d_in[4];
    const float* lg = (const float*)d_in[5];
    const float* lb = (const float*)d_in[6];
    const float* bg = (const float*)d_in[7];
    const float* bb = (const float*)d_in[8];
    const float* tw = (const float*)d_in[9];
    const float* tb = (const float*)d_in[10];
    float* out = (float*)d_out;
    float* ws  = (float*)d_ws;

    float*          h_in  = ws;
    float*          p1f   = ws + 4194304;
    unsigned short* zbf   = (unsigned short*)(ws + 8388608);
    float*          stats = ws + 10485760;
    unsigned short* wAb   = (unsigned short*)(ws + 10486016);
    unsigned short* twB   = (unsigned short*)(ws + 10492160);
    float*          parts = ws + 10498304;
    int*            ib    = (int*)(ws + 10760448);
    int*   mode  = ib;
    int*   hist  = ib + 4;
    int*   rowp  = ib + 2052;
    int*   cur   = ib + 4104;
    int*   csrs  = ib + 6152;
    float* csrw  = (float*)(ib + 38920);

    (void)hipMemsetAsync(ib, 0, 2052 * sizeof(int), stream);   // mode + hist

    k_detect <<<128, 256, 0, stream>>>(ei, mode);
    k_hist   <<<128, 256, 0, stream>>>(ei, mode, hist, cw, wAb, tw, twB);
    k_scan   <<<1,   256, 0, stream>>>(hist, rowp, cur);
    k_scat   <<<128, 256, 0, stream>>>(ei, ew, mode, cur, csrs, csrw);
    k_convln <<<NB,  256, 0, stream>>>(x, wAb, cb, lg, lb, h_in, parts);
    k_bnred  <<<64,  256, 0, stream>>>(parts, bg, bb, stats);
    k_zw0    <<<NB,  256, 0, stream>>>(h_in, stats, twB, tb, zbf, out);
    k_hop1   <<<NB,  256, 0, stream>>>(zbf, rowp, csrs, csrw, twB + 4096, p1f, out);
    k_hop2   <<<NB,  256, 0, stream>>>(p1f, rowp, csrs, csrw, tw + 8192, out);
}